// Round 7
// baseline (659.250 us; speedup 1.0000x reference)
//
#include <hip/hip_runtime.h>
#include <math.h>

#define BB 2
#define NN 512
#define CSZ 384
#define HH 12
#define CC 16
#define PP 8
#define PVV 8
#define KG 16
#define GG 64
#define NCOL 912
#define NODES (BB*NN)

// ---------------- K0: weight prep ----------------
__global__ void k0_prep(const float* __restrict__ Wq, const float* __restrict__ Wkv,
                        const float* __restrict__ Wpq, const float* __restrict__ Wpv,
                        const float* __restrict__ Wkvp,
                        const float* __restrict__ bq, const float* __restrict__ bkv,
                        const float* __restrict__ bpq, const float* __restrict__ bpv,
                        const float* __restrict__ bkvp,
                        const float* __restrict__ ln_g, const float* __restrict__ ln_b,
                        const float* __restrict__ W1, const float* __restrict__ hwin,
                        float* __restrict__ Wbig, float* __restrict__ biasbig,
                        float* __restrict__ P2big, float* __restrict__ W1T,
                        float* __restrict__ hw)
{
  int idx = blockIdx.x*blockDim.x + threadIdx.x;
  int stride = gridDim.x*blockDim.x;
  for (int t = idx; t < CSZ*NCOL; t += stride) {
    int f = t / NCOL, c = t % NCOL;
    float w;
    if (c < 192)      w = Wq[f*192 + c];
    else if (c < 576) w = Wkv[f*384 + (c-192)];
    else if (c < 600) w = ln_g[f]*Wpq[f*24 + (c-576)];
    else if (c < 624) w = ln_g[f]*Wpv[f*24 + (c-600)];
    else              w = Wkvp[f*288 + (c-624)];
    Wbig[t] = w;
  }
  for (int t = idx; t < 64*64; t += stride) {
    int ho = t >> 6, kk = t & 63;
    W1T[t] = W1[kk*64 + ho];
  }
  for (int c = idx; c < NCOL; c += stride) {
    float bb, p2 = 0.f;
    if (c < 192)      bb = bq[c];
    else if (c < 576) bb = bkv[c-192];
    else if (c < 624) {
      const float* W = (c < 600) ? (Wpq + (c-576)) : (Wpv + (c-600));
      float p1 = 0.f;
      for (int f = 0; f < CSZ; ++f) { p1 += ln_b[f]*W[f*24]; p2 += ln_g[f]*W[f*24]; }
      bb = ((c < 600) ? bpq[c-576] : bpv[c-600]) + p1;
    }
    else bb = bkvp[c-624];
    biasbig[c] = bb; P2big[c] = p2;
  }
  for (int h = idx; h < HH; h += stride) {
    float x = hwin[h];
    float sp = (x > 20.f) ? x : log1pf(expf(x));
    hw[h] = sp * sqrtf(1.0f/18.0f) * -0.5f;   // AFS=4, AFS*4.5=18
  }
}

// ---------------- K0b: layernorm stats ----------------
__global__ void k0b_stats(const float* __restrict__ s, float* __restrict__ mout,
                          float* __restrict__ rstdout)
{
  int node = blockIdx.x;
  int l = threadIdx.x;                 // 64 threads = 1 wave
  const float* row = s + node*CSZ;
  float sum = 0.f, sum2 = 0.f;
  for (int f = l; f < CSZ; f += 64) { float v = row[f]; sum += v; sum2 += v*v; }
  #pragma unroll
  for (int off = 1; off < 64; off <<= 1) { sum += __shfl_xor(sum, off); sum2 += __shfl_xor(sum2, off); }
  if (l == 0) {
    float m = sum / CSZ;
    float var = sum2 / CSZ - m*m;
    mout[node] = m;
    rstdout[node] = rsqrtf(var + 1e-5f);
  }
}

// ---------------- K1: fused node GEMM (grid 256: full chip) ----------------
__launch_bounds__(256)
__global__ void k1_gemm(const float* __restrict__ s, const float* __restrict__ Wbig,
                        const float* __restrict__ biasbig, const float* __restrict__ P2big,
                        const float* __restrict__ mrow, const float* __restrict__ rstd,
                        float* __restrict__ act)
{
  const int ROWS = 4;
  int row0 = blockIdx.x * ROWS;   // grid 256
  int t = threadIdx.x;            // 256
  float acc[4][ROWS];
  #pragma unroll
  for (int j = 0; j < 4; ++j)
    #pragma unroll
    for (int r = 0; r < ROWS; ++r) acc[j][r] = 0.f;

  int c3 = t + 768;
  #pragma unroll 4
  for (int f = 0; f < CSZ; ++f) {
    const float* wrow = Wbig + f*NCOL;
    float w0 = wrow[t], w1 = wrow[t+256], w2 = wrow[t+512];
    float w3 = (c3 < NCOL) ? wrow[c3] : 0.f;
    #pragma unroll
    for (int r = 0; r < ROWS; ++r) {
      float sv = s[(row0+r)*CSZ + f];     // uniform -> scalar load
      acc[0][r] = fmaf(sv, w0, acc[0][r]);
      acc[1][r] = fmaf(sv, w1, acc[1][r]);
      acc[2][r] = fmaf(sv, w2, acc[2][r]);
      acc[3][r] = fmaf(sv, w3, acc[3][r]);
    }
  }
  #pragma unroll
  for (int j = 0; j < 4; ++j) {
    int c = t + j*256;
    if (c < NCOL) {
      float bb = biasbig[c], p2v = P2big[c];
      bool lncol = (c >= 576 && c < 624);
      #pragma unroll
      for (int r = 0; r < ROWS; ++r) {
        int node = row0 + r;
        float v;
        if (lncol) { float rs = rstd[node]; v = acc[j][r]*rs + bb - mrow[node]*rs*p2v; }
        else       v = acc[j][r] + bb;
        act[node*NCOL + c] = v;
      }
    }
  }
}

// ---------------- K1b: v transpose + vg compute ----------------
__global__ void k1b_post(const float* __restrict__ act, const float* __restrict__ rot,
                         const float* __restrict__ trans,
                         float* __restrict__ vT, float* __restrict__ vgT)
{
  int idx = blockIdx.x*blockDim.x + threadIdx.x;
  const int NT1 = BB*HH*CC*NN;       // 196608
  const int NT2 = BB*HH*PVV*3*NN;    // 294912
  if (idx < NT1) {
    int n = idx & (NN-1); int rest = idx >> 9;
    int c = rest & 15; rest >>= 4;
    int h = rest % HH; int b = rest / HH;
    int node = b*NN + n;
    vT[idx] = act[node*NCOL + 192 + h*32 + 16 + c];
  } else if (idx < NT1 + NT2) {
    int j = idx - NT1;
    int n = j & (NN-1); int rest = j >> 9;
    int p3 = rest % 24; rest /= 24;
    int h = rest % HH; int b = rest / HH;
    int node = b*NN + n;
    int p = p3 / 3, x = p3 % 3;
    int hp = h*PVV + p;
    const float* kp = act + node*NCOL + 624 + hp*3;
    const float* R = rot + node*9;
    vgT[j] = R[x*3+0]*kp[0] + R[x*3+1]*kp[1] + R[x*3+2]*kp[2] + trans[node*3+x]*0.1f;
  }
}

// ---------------- K2 helper: geometry + vlen for one j ----------------
__device__ __forceinline__ void k2_vlen(const float* __restrict__ act,
                                        const float* __restrict__ rot,
                                        const float* __restrict__ trans,
                                        const float* __restrict__ Wvl,
                                        const float* s_qvec,
                                        const float ri[9], float ti0, float ti1, float ti2,
                                        int jnode, float vlen[8], float& pd)
{
  const float* actj = act + (size_t)jnode*NCOL;
  float rj[9];
  #pragma unroll
  for (int q = 0; q < 9; ++q) rj[q] = rot[(size_t)jnode*9 + q];
  float tj0 = trans[jnode*3], tj1 = trans[jnode*3+1], tj2 = trans[jnode*3+2];

  float Rr[9];
  #pragma unroll
  for (int x = 0; x < 3; ++x)
    #pragma unroll
    for (int z = 0; z < 3; ++z)
      Rr[x*3+z] = ri[x]*rj[z] + ri[3+x]*rj[3+z] + ri[6+x]*rj[6+z];

  float d0 = tj0-ti0, d1 = tj1-ti1, d2 = tj2-ti2;
  pd = 0.01f * (d0*d0 + d1*d1 + d2*d2);
  float tr[3];
  #pragma unroll
  for (int x = 0; x < 3; ++x) tr[x] = ri[x]*d0 + ri[3+x]*d1 + ri[6+x]*d2;

  float vpl[24];
  {
    const float4* v4 = (const float4*)(actj + 600);
    #pragma unroll
    for (int q = 0; q < 6; ++q) {
      float4 x4 = v4[q];
      vpl[q*4+0] = x4.x; vpl[q*4+1] = x4.y; vpl[q*4+2] = x4.z; vpl[q*4+3] = x4.w;
    }
  }
  #pragma unroll
  for (int p = 0; p < PP; ++p) {
    float x0 = vpl[p*3], x1 = vpl[p*3+1], x2 = vpl[p*3+2];
    float l0 = fmaf(Rr[0], x0, fmaf(Rr[1], x1, fmaf(Rr[2], x2, tr[0])));
    float l1 = fmaf(Rr[3], x0, fmaf(Rr[4], x1, fmaf(Rr[5], x2, tr[1])));
    float l2 = fmaf(Rr[6], x0, fmaf(Rr[7], x1, fmaf(Rr[8], x2, tr[2])));
    vpl[p*3] = l0; vpl[p*3+1] = l1; vpl[p*3+2] = l2;
  }
  #pragma unroll
  for (int o = 0; o < 8; ++o) {
    float vx = vpl[o*3+0] + s_qvec[o*3+0];
    float vy = vpl[o*3+1] + s_qvec[o*3+1];
    float vz = vpl[o*3+2] + s_qvec[o*3+2];
    #pragma unroll
    for (int p = 0; p < PP; ++p) {
      float w = Wvl[o*16+p];          // uniform -> scalar (256B, sL1-resident)
      vx = fmaf(w, vpl[p*3+0], vx);
      vy = fmaf(w, vpl[p*3+1], vy);
      vz = fmaf(w, vpl[p*3+2], vz);
    }
    vlen[o] = sqrtf(vx*vx + vy*vy + vz*vz + 1e-8f);
  }
}

// ---------------- K2: fused pair kernel — LDS weights + NJ=2 ----------------
// grid 1024 = (b,i); 256 threads; thread t handles j=t and j=t+256.
// LDS-pipe model (validated r2/r5): dur_floor = b128/wave * waves_per_CU * 12cy
// = 3072 * 16 * 12 = 246us. r5 measured 342: VGPR=112 -> allocator parked acc
// in AGPRs (+accvgpr moves: VALU 193us vs 89 floor) + ~334MB setup spills.
// amdgpu_waves_per_eu(1,2) caps the occupancy target at 2 waves/EU -> per-wave
// budget 256 VGPRs, so acc0+acc1 (128) + in-flight LDS regs live in ARCH VGPRs.
// (r5 occupancy was 6.9 waves/CU; the 8-wave cap costs nothing.)
__attribute__((amdgpu_waves_per_eu(1, 2)))
__launch_bounds__(256)
__global__ void k2_pair(const float* __restrict__ act, const float* __restrict__ rot,
                        const float* __restrict__ trans, const float* __restrict__ mask,
                        const float* __restrict__ Wvl, const float* __restrict__ gm_in,
                        const float* __restrict__ gs_in,
                        const float* __restrict__ Wg, const float* __restrict__ bg,
                        const float* __restrict__ W1T, const float* __restrict__ b1,
                        const float* __restrict__ W2, const float* __restrict__ b2,
                        const float* __restrict__ hw,
                        float* __restrict__ gout, float* __restrict__ apre)
{
  __shared__ __align__(16) float s_wg[128*64];    // 32 KB
  __shared__ __align__(16) float s_w1t[64*64];    // 16 KB
  __shared__ float s_qvec[PP*3];
  __shared__ float s_gm[KG], s_gis[KG];
  __shared__ float s_hw[HH];

  int bi = blockIdx.x;              // b*512 + i
  int b = bi >> 9, i = bi & (NN-1);
  int t = threadIdx.x;              // 256
  const float* acti = act + (size_t)bi*NCOL;

  // ---- stage weights to LDS (coalesced float4) ----
  {
    const float4* wg4 = (const float4*)Wg;
    float4* d4 = (float4*)s_wg;
    #pragma unroll
    for (int q = 0; q < 8; ++q) d4[t + 256*q] = wg4[t + 256*q];     // 2048 float4
    const float4* w14 = (const float4*)W1T;
    float4* e4 = (float4*)s_w1t;
    #pragma unroll
    for (int q = 0; q < 4; ++q) e4[t + 256*q] = w14[t + 256*q];     // 1024 float4
  }
  if (t < 24) {
    int o = t / 3, c = t % 3;
    float sum = 0.f;
    #pragma unroll
    for (int p = 0; p < PP; ++p) sum += Wvl[o*16 + 8 + p] * acti[576 + p*3 + c];
    s_qvec[t] = sum;
  } else if (t >= 32 && t < 48) {
    int k = t - 32; s_gm[k] = gm_in[k]; s_gis[k] = 1.f / gs_in[k];
  } else if (t >= 64 && t < 76) {
    s_hw[t-64] = hw[t-64];
  }
  __syncthreads();

  // block-uniform (scalar) data
  const float* Ri = rot + (size_t)bi*9;
  float ri[9];
  #pragma unroll
  for (int q = 0; q < 9; ++q) ri[q] = Ri[q];
  float ti0 = trans[bi*3], ti1 = trans[bi*3+1], ti2 = trans[bi*3+2];
  float mi = mask[bi];

  int j0 = t, j1 = t + 256;
  int jn0 = b*NN + j0, jn1 = b*NN + j1;

  float vlen0[8], vlen1[8];
  float pd0, pd1;
  k2_vlen(act, rot, trans, Wvl, s_qvec, ri, ti0, ti1, ti2, jn0, vlen0, pd0);
  k2_vlen(act, rot, trans, Wvl, s_qvec, ri, ti0, ti1, ti2, jn1, vlen1, pd1);

  // ---- g = gauss @ Wg + bg (LDS weight broadcast; one fetch -> 128 FMAs) ----
  float acc0[64], acc1[64];
  #pragma unroll
  for (int q = 0; q < 64; ++q) { float bb = bg[q]; acc0[q] = bb; acc1[q] = bb; }

  #pragma unroll 1
  for (int o = 0; o < 8; ++o) {
    float vlo0 = vlen0[o], vlo1 = vlen1[o];
    const float* wbase = s_wg + o*KG*64;
    #pragma unroll 1
    for (int k = 0; k < KG; ++k) {
      float t0 = (vlo0 - s_gm[k]) * s_gis[k];
      float t1 = (vlo1 - s_gm[k]) * s_gis[k];
      float gk0 = __expf(-0.5f * t0 * t0);
      float gk1 = __expf(-0.5f * t1 * t1);
      const float4* wr4 = (const float4*)(wbase + k*64);
      #pragma unroll
      for (int q = 0; q < 16; ++q) {
        float4 w4 = wr4[q];
        acc0[4*q+0] = fmaf(gk0, w4.x, acc0[4*q+0]);
        acc0[4*q+1] = fmaf(gk0, w4.y, acc0[4*q+1]);
        acc0[4*q+2] = fmaf(gk0, w4.z, acc0[4*q+2]);
        acc0[4*q+3] = fmaf(gk0, w4.w, acc0[4*q+3]);
        acc1[4*q+0] = fmaf(gk1, w4.x, acc1[4*q+0]);
        acc1[4*q+1] = fmaf(gk1, w4.y, acc1[4*q+1]);
        acc1[4*q+2] = fmaf(gk1, w4.z, acc1[4*q+2]);
        acc1[4*q+3] = fmaf(gk1, w4.w, acc1[4*q+3]);
      }
    }
  }

  // write g (output 1)
  {
    float4* g0 = (float4*)(gout + ((size_t)bi*NN + j0)*64);
    float4* g1 = (float4*)(gout + ((size_t)bi*NN + j1)*64);
    #pragma unroll
    for (int q = 0; q < 16; ++q) {
      g0[q] = make_float4(acc0[4*q], acc0[4*q+1], acc0[4*q+2], acc0[4*q+3]);
      g1[q] = make_float4(acc1[4*q], acc1[4*q+1], acc1[4*q+2], acc1[4*q+3]);
    }
  }

  // ---- vfn = relu(g@W1+b1)@W2 + b2 (LDS W1T broadcast, NJ=2) ----
  float vf0[12], vf1[12];
  #pragma unroll
  for (int hh = 0; hh < 12; ++hh) { float bb = b2[hh]; vf0[hh] = bb; vf1[hh] = bb; }
  #pragma unroll 1
  for (int ho = 0; ho < 64; ++ho) {
    const float4* w1r = (const float4*)(s_w1t + ho*64);
    float bb1 = b1[ho];
    float a0 = bb1, b0 = 0.f, a1 = bb1, b1v = 0.f;
    #pragma unroll
    for (int q = 0; q < 8; ++q) {
      float4 wa = w1r[q];
      float4 wb = w1r[q+8];
      a0 = fmaf(acc0[4*q+0],  wa.x, a0); a0 = fmaf(acc0[4*q+1],  wa.y, a0);
      a0 = fmaf(acc0[4*q+2],  wa.z, a0); a0 = fmaf(acc0[4*q+3],  wa.w, a0);
      b0 = fmaf(acc0[32+4*q+0], wb.x, b0); b0 = fmaf(acc0[32+4*q+1], wb.y, b0);
      b0 = fmaf(acc0[32+4*q+2], wb.z, b0); b0 = fmaf(acc0[32+4*q+3], wb.w, b0);
      a1 = fmaf(acc1[4*q+0],  wa.x, a1); a1 = fmaf(acc1[4*q+1],  wa.y, a1);
      a1 = fmaf(acc1[4*q+2],  wa.z, a1); a1 = fmaf(acc1[4*q+3],  wa.w, a1);
      b1v = fmaf(acc1[32+4*q+0], wb.x, b1v); b1v = fmaf(acc1[32+4*q+1], wb.y, b1v);
      b1v = fmaf(acc1[32+4*q+2], wb.z, b1v); b1v = fmaf(acc1[32+4*q+3], wb.w, b1v);
    }
    float hs0 = fmaxf(a0 + b0, 0.f);
    float hs1 = fmaxf(a1 + b1v, 0.f);
    const float* w2r = W2 + ho*12;     // uniform -> scalar (3KB, sL1-resident)
    #pragma unroll
    for (int hh = 0; hh < 12; ++hh) {
      float wv = w2r[hh];
      vf0[hh] = fmaf(hs0, wv, vf0[hh]);
      vf1[hh] = fmaf(hs1, wv, vf1[hh]);
    }
  }

  // ---- qk + combine + write, per j ----
  const float* actj0 = act + (size_t)jn0*NCOL;
  const float* actj1 = act + (size_t)jn1*NCOL;
  float mj0 = mask[jn0], mj1 = mask[jn1];
  float mt0 = 100000.f * (mi*mj0 - 1.f);
  float mt1 = 100000.f * (mi*mj1 - 1.f);
  #pragma unroll
  for (int h = 0; h < 12; ++h) {
    const float4* k40 = (const float4*)(actj0 + 192 + h*32);
    const float4* k41 = (const float4*)(actj1 + 192 + h*32);
    float q0 = 0.f, q1 = 0.f;
    #pragma unroll
    for (int q = 0; q < 4; ++q) {
      float4 kv0 = k40[q];
      float4 kv1 = k41[q];
      const float* qp = acti + h*16 + q*4;   // uniform -> scalar
      q0 = fmaf(qp[0], kv0.x, q0); q0 = fmaf(qp[1], kv0.y, q0);
      q0 = fmaf(qp[2], kv0.z, q0); q0 = fmaf(qp[3], kv0.w, q0);
      q1 = fmaf(qp[0], kv1.x, q1); q1 = fmaf(qp[1], kv1.y, q1);
      q1 = fmaf(qp[2], kv1.z, q1); q1 = fmaf(qp[3], kv1.w, q1);
    }
    float* arow = apre + (((size_t)b*HH + h)*NN + i)*NN;
    arow[j0] = q0*0.125f + vf0[h]*0.5f + pd0*s_hw[h] + mt0;
    arow[j1] = q1*0.125f + vf1[h]*0.5f + pd1*s_hw[h] + mt1;
  }
}

// ---------------- K3: softmax + attend ----------------
__launch_bounds__(256)
__global__ void k3_attend(const float* __restrict__ apre, const float* __restrict__ vT,
                          const float* __restrict__ vgT,
                          float* __restrict__ oout, float* __restrict__ optout)
{
  __shared__ float a4t[4][NN];     // transposed: conflict-free b32 reads
  int blk = blockIdx.x;            // B*H*(N/4)
  int ic = blk & 127; int rest = blk >> 7;
  int h = rest % HH; int b = rest / HH;
  int i0 = ic * 4;
  int t = threadIdx.x; int w = t >> 6; int l = t & 63;

  { // phase 1: wave w -> row i0+w
    int i = i0 + w;
    const float* row = apre + (((size_t)b*HH + h)*NN + i)*NN;
    float vals[8];
    float m = -1e30f;
    #pragma unroll
    for (int s8 = 0; s8 < 8; ++s8) { vals[s8] = row[l + 64*s8]; m = fmaxf(m, vals[s8]); }
    #pragma unroll
    for (int off = 1; off < 64; off <<= 1) m = fmaxf(m, __shfl_xor(m, off));
    float sum = 0.f;
    #pragma unroll
    for (int s8 = 0; s8 < 8; ++s8) { vals[s8] = __expf(vals[s8] - m); sum += vals[s8]; }
    #pragma unroll
    for (int off = 1; off < 64; off <<= 1) sum += __shfl_xor(sum, off);
    float inv = 1.f / sum;
    #pragma unroll
    for (int s8 = 0; s8 < 8; ++s8) a4t[w][l + 64*s8] = vals[s8] * inv;
  }
  __syncthreads();

  const float* vbase = vT + ((size_t)(b*HH + h)*CC)*NN;
  const float* gbase = vgT + ((size_t)(b*HH + h)*24)*NN;
  #pragma unroll 1
  for (int pass = 0; pass < 5; ++pass) {
    int c0 = w + 8*pass;
    int c1 = c0 + 4;
    const float* s0 = (c0 < 16) ? (vbase + c0*NN) : (gbase + (c0-16)*NN);
    const float* s1 = (c1 < 16) ? (vbase + c1*NN) : (gbase + (c1-16)*NN);
    float acc0[4] = {0,0,0,0}, acc1[4] = {0,0,0,0};
    #pragma unroll
    for (int s8 = 0; s8 < 8; ++s8) {
      int j = l + 64*s8;
      float a0 = a4t[0][j], a1 = a4t[1][j], a2 = a4t[2][j], a3 = a4t[3][j];
      float v0 = s0[j], v1 = s1[j];
      acc0[0] = fmaf(a0, v0, acc0[0]); acc0[1] = fmaf(a1, v0, acc0[1]);
      acc0[2] = fmaf(a2, v0, acc0[2]); acc0[3] = fmaf(a3, v0, acc0[3]);
      acc1[0] = fmaf(a0, v1, acc1[0]); acc1[1] = fmaf(a1, v1, acc1[1]);
      acc1[2] = fmaf(a2, v1, acc1[2]); acc1[3] = fmaf(a3, v1, acc1[3]);
    }
    #pragma unroll
    for (int r = 0; r < 4; ++r) {
      #pragma unroll
      for (int off = 1; off < 64; off <<= 1) {
        acc0[r] += __shfl_xor(acc0[r], off);
        acc1[r] += __shfl_xor(acc1[r], off);
      }
    }
    if (l == 0) {
      #pragma unroll
      for (int r = 0; r < 4; ++r) {
        int node = b*NN + i0 + r;
        if (c0 < 16) oout[node*192 + h*16 + c0] = acc0[r];
        else         optout[node*288 + h*24 + (c0-16)] = acc0[r];
        if (c1 < 16) oout[node*192 + h*16 + c1] = acc1[r];
        else         optout[node*288 + h*24 + (c1-16)] = acc1[r];
      }
    }
  }
}

// ---------------- K4a: build feats ----------------
__global__ void k4a_feats(const float* __restrict__ oo, const float* __restrict__ opt,
                          const float* __restrict__ rot, const float* __restrict__ trans,
                          float* __restrict__ feats)
{
  int node = blockIdx.x; int t = threadIdx.x;   // 320 threads
  float* fr = feats + node*576;
  if (t < 192) {
    fr[t] = oo[node*192 + t];
  } else if (t < 288) {
    int hp = t - 192;
    const float* R = rot + node*9;
    float tx = trans[node*3+0]*0.1f, ty = trans[node*3+1]*0.1f, tz = trans[node*3+2]*0.1f;
    const float* op = opt + (node*96 + hp)*3;
    float px = op[0]-tx, py = op[1]-ty, pz = op[2]-tz;
    float lx = R[0]*px + R[3]*py + R[6]*pz;
    float ly = R[1]*px + R[4]*py + R[7]*pz;
    float lz = R[2]*px + R[5]*py + R[8]*pz;
    float d = sqrtf(lx*lx + ly*ly + lz*lz + 1e-8f);
    fr[192+hp] = lx; fr[288+hp] = ly; fr[384+hp] = lz; fr[480+hp] = d;
  }
}

// ---------------- K4b: output projection (grid 256: full chip) ----------------
__launch_bounds__(384)
__global__ void k4b_out(const float* __restrict__ feats, const float* __restrict__ Wout,
                        const float* __restrict__ bout, float* __restrict__ sout)
{
  const int ROWS = 4;
  int row0 = blockIdx.x * ROWS;   // grid 256
  int c = threadIdx.x;            // 384
  float acc[ROWS];
  #pragma unroll
  for (int r = 0; r < ROWS; ++r) acc[r] = 0.f;
  #pragma unroll 4
  for (int f = 0; f < 576; ++f) {
    float wv = Wout[f*384 + c];
    #pragma unroll
    for (int r = 0; r < ROWS; ++r)
      acc[r] = fmaf(feats[(row0+r)*576 + f], wv, acc[r]);   // feats uniform -> scalar
  }
  float bb = bout[c];
  #pragma unroll
  for (int r = 0; r < ROWS; ++r) sout[(row0+r)*384 + c] = acc[r] + bb;
}

// ---------------- launch ----------------
extern "C" void kernel_launch(void* const* d_in, const int* in_sizes, int n_in,
                              void* d_out, int out_size, void* d_ws, size_t ws_size,
                              hipStream_t stream)
{
  const float* s     = (const float*)d_in[0];
  const float* rot   = (const float*)d_in[1];
  const float* trans = (const float*)d_in[2];
  const float* mask  = (const float*)d_in[3];
  const float* Wq    = (const float*)d_in[4];
  const float* bq    = (const float*)d_in[5];
  const float* Wkv   = (const float*)d_in[6];
  const float* bkv   = (const float*)d_in[7];
  const float* hwts  = (const float*)d_in[8];
  const float* ln_g  = (const float*)d_in[9];
  const float* ln_b  = (const float*)d_in[10];
  const float* Wpq   = (const float*)d_in[11];
  const float* bpq   = (const float*)d_in[12];
  const float* Wpv   = (const float*)d_in[13];
  const float* bpv   = (const float*)d_in[14];
  const float* Wvl   = (const float*)d_in[15];
  const float* gbm   = (const float*)d_in[16];
  const float* gbs   = (const float*)d_in[17];
  const float* Wg    = (const float*)d_in[18];
  const float* bg    = (const float*)d_in[19];
  const float* W1    = (const float*)d_in[20];
  const float* b1    = (const float*)d_in[21];
  const float* W2    = (const float*)d_in[22];
  const float* b2    = (const float*)d_in[23];
  const float* Wkvp  = (const float*)d_in[24];
  const float* bkvp  = (const float*)d_in[25];
  const float* Wout  = (const float*)d_in[26];
  const float* bout  = (const float*)d_in[27];

  float* ws = (float*)d_ws;
  float* act   = ws + 0;          // 1024*912
  float* Wbig  = ws + 933888;     // 384*912
  float* bias  = ws + 1284096;    // 912
  float* P2    = ws + 1285008;    // 912
  float* W1T   = ws + 1285920;    // 4096
  float* hw    = ws + 1290016;    // 16
  float* mrow  = ws + 1290032;    // 1024
  float* rstd  = ws + 1291056;    // 1024
  float* vT    = ws + 1292080;    // 196608
  float* vgT   = ws + 1488688;    // 294912
  float* apre  = ws + 1783600;    // 6291456
  float* oo    = ws + 8075056;    // 196608
  float* opt   = ws + 8271664;    // 294912
  float* feats = ws + 8566576;    // 589824  (end 9156400 floats = 36.6 MB)

  float* sout = (float*)d_out;
  float* gout = sout + BB*NN*CSZ;   // g at offset 393216

  hipLaunchKernelGGL(k0_prep, dim3(256), dim3(256), 0, stream,
                     Wq, Wkv, Wpq, Wpv, Wkvp, bq, bkv, bpq, bpv, bkvp,
                     ln_g, ln_b, W1, hwts, Wbig, bias, P2, W1T, hw);
  hipLaunchKernelGGL(k0b_stats, dim3(1024), dim3(64), 0, stream, s, mrow, rstd);
  hipLaunchKernelGGL(k1_gemm, dim3(256), dim3(256), 0, stream,
                     s, Wbig, bias, P2, mrow, rstd, act);
  hipLaunchKernelGGL(k1b_post, dim3(1920), dim3(256), 0, stream, act, rot, trans, vT, vgT);
  hipLaunchKernelGGL(k2_pair, dim3(1024), dim3(256), 0, stream,
                     act, rot, trans, mask, Wvl, gbm, gbs, Wg, bg, W1T, b1, W2, b2, hw,
                     gout, apre);
  hipLaunchKernelGGL(k3_attend, dim3(3072), dim3(256), 0, stream, apre, vT, vgT, oo, opt);
  hipLaunchKernelGGL(k4a_feats, dim3(1024), dim3(320), 0, stream, oo, opt, rot, trans, feats);
  hipLaunchKernelGGL(k4b_out, dim3(256), dim3(384), 0, stream, feats, Wout, bout, sout);
}

// Round 8
// 569.586 us; speedup vs baseline: 1.1574x; 1.1574x over previous
//
#include <hip/hip_runtime.h>
#include <math.h>

#define BB 2
#define NN 512
#define CSZ 384
#define HH 12
#define CC 16
#define PP 8
#define PVV 8
#define KG 16
#define GG 64
#define NCOL 912
#define NODES (BB*NN)

typedef __attribute__((ext_vector_type(8))) short bf16x8;
typedef __attribute__((ext_vector_type(4))) float floatx4;

__device__ __forceinline__ unsigned short f2bf(float x) {
  unsigned u = __float_as_uint(x);
  unsigned r = (u + 0x7FFF + ((u >> 16) & 1)) >> 16;   // RNE
  return (unsigned short)r;
}

// ---------------- K0: weight prep ----------------
__global__ void k0_prep(const float* __restrict__ Wq, const float* __restrict__ Wkv,
                        const float* __restrict__ Wpq, const float* __restrict__ Wpv,
                        const float* __restrict__ Wkvp,
                        const float* __restrict__ bq, const float* __restrict__ bkv,
                        const float* __restrict__ bpq, const float* __restrict__ bpv,
                        const float* __restrict__ bkvp,
                        const float* __restrict__ ln_g, const float* __restrict__ ln_b,
                        const float* __restrict__ W1, const float* __restrict__ hwin,
                        const float* __restrict__ Wg, const float* __restrict__ W2,
                        float* __restrict__ Wbig, float* __restrict__ biasbig,
                        float* __restrict__ P2big, unsigned short* __restrict__ wbf,
                        float* __restrict__ hw)
{
  int idx = blockIdx.x*blockDim.x + threadIdx.x;
  int stride = gridDim.x*blockDim.x;
  for (int t = idx; t < CSZ*NCOL; t += stride) {
    int f = t / NCOL, c = t % NCOL;
    float w;
    if (c < 192)      w = Wq[f*192 + c];
    else if (c < 576) w = Wkv[f*384 + (c-192)];
    else if (c < 600) w = ln_g[f]*Wpq[f*24 + (c-576)];
    else if (c < 624) w = ln_g[f]*Wpv[f*24 + (c-600)];
    else              w = Wkvp[f*288 + (c-624)];
    Wbig[t] = w;
  }
  // bf16 weight pack for MFMA k2:
  // [0..8191] WgT hi [ch][pk], [8192..16383] WgT lo, [16384..20479] W1T [ho][k], [20480..21503] W2T [head][ho]
  for (int t = idx; t < 8192; t += stride) {
    int ch = t >> 7, pk = t & 127;
    float wv = Wg[pk*64 + ch];
    unsigned short h = f2bf(wv);
    float hf = __uint_as_float(((unsigned)h) << 16);
    wbf[t] = h;
    wbf[8192 + t] = f2bf(wv - hf);
  }
  for (int t = idx; t < 4096; t += stride) {
    int ho = t >> 6, k = t & 63;
    wbf[16384 + t] = f2bf(W1[k*64 + ho]);
  }
  for (int t = idx; t < 1024; t += stride) {
    int hh = t >> 6, ho = t & 63;
    wbf[20480 + t] = (hh < 12) ? f2bf(W2[ho*12 + hh]) : (unsigned short)0;
  }
  for (int c = idx; c < NCOL; c += stride) {
    float bb, p2 = 0.f;
    if (c < 192)      bb = bq[c];
    else if (c < 576) bb = bkv[c-192];
    else if (c < 624) {
      const float* W = (c < 600) ? (Wpq + (c-576)) : (Wpv + (c-600));
      float p1 = 0.f;
      for (int f = 0; f < CSZ; ++f) { p1 += ln_b[f]*W[f*24]; p2 += ln_g[f]*W[f*24]; }
      bb = ((c < 600) ? bpq[c-576] : bpv[c-600]) + p1;
    }
    else bb = bkvp[c-624];
    biasbig[c] = bb; P2big[c] = p2;
  }
  for (int h = idx; h < HH; h += stride) {
    float x = hwin[h];
    float sp = (x > 20.f) ? x : log1pf(expf(x));
    hw[h] = sp * sqrtf(1.0f/18.0f) * -0.5f;   // AFS=4, AFS*4.5=18
  }
}

// ---------------- K0b: layernorm stats ----------------
__global__ void k0b_stats(const float* __restrict__ s, float* __restrict__ mout,
                          float* __restrict__ rstdout)
{
  int node = blockIdx.x;
  int l = threadIdx.x;                 // 64 threads = 1 wave
  const float* row = s + node*CSZ;
  float sum = 0.f, sum2 = 0.f;
  for (int f = l; f < CSZ; f += 64) { float v = row[f]; sum += v; sum2 += v*v; }
  #pragma unroll
  for (int off = 1; off < 64; off <<= 1) { sum += __shfl_xor(sum, off); sum2 += __shfl_xor(sum2, off); }
  if (l == 0) {
    float m = sum / CSZ;
    float var = sum2 / CSZ - m*m;
    mout[node] = m;
    rstdout[node] = rsqrtf(var + 1e-5f);
  }
}

// ---------------- K1: fused node GEMM (grid 256) ----------------
__launch_bounds__(256)
__global__ void k1_gemm(const float* __restrict__ s, const float* __restrict__ Wbig,
                        const float* __restrict__ biasbig, const float* __restrict__ P2big,
                        const float* __restrict__ mrow, const float* __restrict__ rstd,
                        float* __restrict__ act)
{
  const int ROWS = 4;
  int row0 = blockIdx.x * ROWS;   // grid 256
  int t = threadIdx.x;            // 256
  float acc[4][ROWS];
  #pragma unroll
  for (int j = 0; j < 4; ++j)
    #pragma unroll
    for (int r = 0; r < ROWS; ++r) acc[j][r] = 0.f;

  int c3 = t + 768;
  #pragma unroll 4
  for (int f = 0; f < CSZ; ++f) {
    const float* wrow = Wbig + f*NCOL;
    float w0 = wrow[t], w1 = wrow[t+256], w2 = wrow[t+512];
    float w3 = (c3 < NCOL) ? wrow[c3] : 0.f;
    #pragma unroll
    for (int r = 0; r < ROWS; ++r) {
      float sv = s[(row0+r)*CSZ + f];     // uniform -> scalar load
      acc[0][r] = fmaf(sv, w0, acc[0][r]);
      acc[1][r] = fmaf(sv, w1, acc[1][r]);
      acc[2][r] = fmaf(sv, w2, acc[2][r]);
      acc[3][r] = fmaf(sv, w3, acc[3][r]);
    }
  }
  #pragma unroll
  for (int j = 0; j < 4; ++j) {
    int c = t + j*256;
    if (c < NCOL) {
      float bb = biasbig[c], p2v = P2big[c];
      bool lncol = (c >= 576 && c < 624);
      #pragma unroll
      for (int r = 0; r < ROWS; ++r) {
        int node = row0 + r;
        float v;
        if (lncol) { float rs = rstd[node]; v = acc[j][r]*rs + bb - mrow[node]*rs*p2v; }
        else       v = acc[j][r] + bb;
        act[node*NCOL + c] = v;
      }
    }
  }
}

// ---------------- K1b: v transpose + vg compute ----------------
__global__ void k1b_post(const float* __restrict__ act, const float* __restrict__ rot,
                         const float* __restrict__ trans,
                         float* __restrict__ vT, float* __restrict__ vgT)
{
  int idx = blockIdx.x*blockDim.x + threadIdx.x;
  const int NT1 = BB*HH*CC*NN;       // 196608
  const int NT2 = BB*HH*PVV*3*NN;    // 294912
  if (idx < NT1) {
    int n = idx & (NN-1); int rest = idx >> 9;
    int c = rest & 15; rest >>= 4;
    int h = rest % HH; int b = rest / HH;
    int node = b*NN + n;
    vT[idx] = act[node*NCOL + 192 + h*32 + 16 + c];
  } else if (idx < NT1 + NT2) {
    int j = idx - NT1;
    int n = j & (NN-1); int rest = j >> 9;
    int p3 = rest % 24; rest /= 24;
    int h = rest % HH; int b = rest / HH;
    int node = b*NN + n;
    int p = p3 / 3, x = p3 % 3;
    int hp = h*PVV + p;
    const float* kp = act + node*NCOL + 624 + hp*3;
    const float* R = rot + node*9;
    vgT[j] = R[x*3+0]*kp[0] + R[x*3+1]*kp[1] + R[x*3+2]*kp[2] + trans[node*3+x]*0.1f;
  }
}

// ---------------- K2: MFMA pair kernel ----------------
// grid 1024 = (b,i); 256 threads (4 waves). Per block: 4 j-tiles of 128.
// Phases per tile: T1 VALU geometry+gauss(bf16, swizzled LDS) | T2 MFMA g =
// gauss@ (WgHi+WgLo) [wave n-split, 16 ch each] -> gout + bf16 g tile |
// T3 MFMA h = relu(g@W1+b1) | T4 MFMA vfn = h@W2+b2 [wave m-split] |
// T5 VALU qk+pd+mask -> apre.
// Rationale: r0-r7 showed the VALU structure is floored at ~225us by the
// wave-uniform weight-delivery stream (scalar/LDS/VMEM all fail) and the
// allocator caps arch VGPRs at ~148. MFMA removes both: weights live in
// B-frags (AGPR-ok), FMA work moves to the matrix pipe.
// Precision: Wg split hi/lo bf16 (exact), gauss RNE bf16 (rel 2^-9) ->
// g err RMS ~1e-4 << 7.8e-3 tol; W1/W2 single bf16 (feeds 0.5-scaled logits).
__launch_bounds__(256)
__global__ void k2_pair(const float* __restrict__ act, const float* __restrict__ rot,
                        const float* __restrict__ trans, const float* __restrict__ mask,
                        const float* __restrict__ Wvl, const float* __restrict__ gm_in,
                        const float* __restrict__ gs_in,
                        const unsigned short* __restrict__ wbf,
                        const float* __restrict__ bg, const float* __restrict__ b1,
                        const float* __restrict__ b2, const float* __restrict__ hw,
                        float* __restrict__ gout, float* __restrict__ apre)
{
  // s_gauss aliased at start: WgT hi [0..8191], WgT lo [8192..16383] (ushort idx)
  __shared__ __align__(16) unsigned short s_gauss[128*128];   // 32 KB
  // s_gh aliased at start: W1T [0..4095], W2T [4096..5119]
  __shared__ __align__(16) unsigned short s_gh[128*64];       // 16 KB
  __shared__ float s_qvec[24];
  __shared__ float s_q[192];
  __shared__ float s_wvl[128];
  __shared__ float s_gm[KG], s_gis[KG];
  __shared__ float s_hw[HH];

  int bi = blockIdx.x;              // b*512 + i
  int b = bi >> 9, i = bi & (NN-1);
  int t = threadIdx.x;
  int w = t >> 6, l = t & 63;
  int lo = l & 15, hi4 = l >> 4;    // C/D: col=lo, row=(hi4)*4+r  [m89 verified]
  const float* acti = act + (size_t)bi*NCOL;

  // ---- stage weights to LDS (transient aliasing) ----
  {
    const uint4* src = (const uint4*)wbf;
    uint4* d1 = (uint4*)s_gauss;                 // 2048 uint4 = WgT hi+lo
    for (int q = t; q < 2048; q += 256) d1[q] = src[q];
    uint4* d2 = (uint4*)s_gh;                    // 640 uint4 = W1T + W2T
    for (int q = t; q < 640; q += 256) d2[q] = src[2048 + q];
  }
  if (t < 24) {
    int o = t / 3, c = t % 3;
    float sum = 0.f;
    #pragma unroll
    for (int p = 0; p < PP; ++p) sum += Wvl[o*16 + 8 + p] * acti[576 + p*3 + c];
    s_qvec[t] = sum;
  } else if (t >= 32 && t < 48) {
    int k = t - 32; s_gm[k] = gm_in[k]; s_gis[k] = 1.f / gs_in[k];
  } else if (t >= 64 && t < 76) {
    s_hw[t-64] = hw[t-64];
  }
  if (t < 192) s_q[t] = acti[t];       // q rows (act cols 0..191)
  if (t < 128) s_wvl[t] = Wvl[t];
  __syncthreads();

  // ---- preload B-frags (B: lane holds B[k=(l>>4)*8+e][col=l&15]) ----
  int n0 = w*16;
  bf16x8 wgf[8];   // [kr*2 + (0=hi,1=lo)]
  {
    const char* base = (const char*)s_gauss;
    #pragma unroll
    for (int kr = 0; kr < 4; ++kr) {
      int byt = ((n0+lo)*128 + kr*32 + hi4*8)*2;
      wgf[kr*2+0] = *(const bf16x8*)(base + byt);             // hi plane
      wgf[kr*2+1] = *(const bf16x8*)(base + 16384 + byt);     // lo plane (+8192 ushort)
    }
  }
  bf16x8 w1f[2], w2f[2];
  {
    const char* base = (const char*)s_gh;
    #pragma unroll
    for (int kr = 0; kr < 2; ++kr)
      w1f[kr] = *(const bf16x8*)(base + ((n0+lo)*64 + kr*32 + hi4*8)*2);
    const char* base2 = (const char*)s_gh + 4096*2;
    #pragma unroll
    for (int kr = 0; kr < 2; ++kr)
      w2f[kr] = *(const bf16x8*)(base2 + (lo*64 + kr*32 + hi4*8)*2);
  }

  // per-lane persistent scalars
  float bgv = bg[n0 + lo];
  float b1v = b1[n0 + lo];
  int head = lo;
  float b2v = (head < 12) ? b2[head] : 0.f;
  float hwv = s_hw[(head < 12) ? head : 0];
  float mi = mask[bi];
  float ti0 = trans[bi*3], ti1 = trans[bi*3+1], ti2 = trans[bi*3+2];
  float ri[9];
  #pragma unroll
  for (int q = 0; q < 9; ++q) ri[q] = rot[(size_t)bi*9 + q];
  float qv[16];
  {
    int hq = (head < 12) ? head : 0;
    #pragma unroll
    for (int c = 0; c < 16; ++c) qv[c] = s_q[hq*16 + c];
  }
  __syncthreads();   // frag preload done before T1 overwrites weight regions

  char* gb = (char*)s_gauss;
  char* hb = (char*)s_gh;

  for (int tt = 0; tt < 4; ++tt) {
    int jt0 = tt*128;

    // ---- T1: geometry + vlen + gauss (bf16, swizzled) ----
    {
      int jo = t >> 1, kh = t & 1;          // thread -> (j-offset, k-half)
      int jnode = b*NN + jt0 + jo;
      const float* actj = act + (size_t)jnode*NCOL;
      float rj[9];
      #pragma unroll
      for (int q = 0; q < 9; ++q) rj[q] = rot[(size_t)jnode*9 + q];
      float d0 = trans[jnode*3]-ti0, d1 = trans[jnode*3+1]-ti1, d2 = trans[jnode*3+2]-ti2;
      float Rr[9];
      #pragma unroll
      for (int x = 0; x < 3; ++x)
        #pragma unroll
        for (int z = 0; z < 3; ++z)
          Rr[x*3+z] = ri[x]*rj[z] + ri[3+x]*rj[3+z] + ri[6+x]*rj[6+z];
      float tr[3];
      #pragma unroll
      for (int x = 0; x < 3; ++x) tr[x] = ri[x]*d0 + ri[3+x]*d1 + ri[6+x]*d2;
      float vpl[24];
      {
        const float4* v4 = (const float4*)(actj + 600);
        #pragma unroll
        for (int q = 0; q < 6; ++q) {
          float4 x4 = v4[q];
          vpl[q*4+0] = x4.x; vpl[q*4+1] = x4.y; vpl[q*4+2] = x4.z; vpl[q*4+3] = x4.w;
        }
      }
      #pragma unroll
      for (int p = 0; p < PP; ++p) {
        float x0 = vpl[p*3], x1 = vpl[p*3+1], x2 = vpl[p*3+2];
        float l0 = fmaf(Rr[0], x0, fmaf(Rr[1], x1, fmaf(Rr[2], x2, tr[0])));
        float l1 = fmaf(Rr[3], x0, fmaf(Rr[4], x1, fmaf(Rr[5], x2, tr[1])));
        float l2 = fmaf(Rr[6], x0, fmaf(Rr[7], x1, fmaf(Rr[8], x2, tr[2])));
        vpl[p*3] = l0; vpl[p*3+1] = l1; vpl[p*3+2] = l2;
      }
      #pragma unroll
      for (int oo = 0; oo < 4; ++oo) {
        int o = kh*4 + oo;
        float vx = vpl[o*3+0] + s_qvec[o*3+0];
        float vy = vpl[o*3+1] + s_qvec[o*3+1];
        float vz = vpl[o*3+2] + s_qvec[o*3+2];
        #pragma unroll
        for (int p = 0; p < PP; ++p) {
          float wv = s_wvl[o*16+p];
          vx = fmaf(wv, vpl[p*3+0], vx);
          vy = fmaf(wv, vpl[p*3+1], vy);
          vz = fmaf(wv, vpl[p*3+2], vz);
        }
        float vlen = sqrtf(vx*vx + vy*vy + vz*vz + 1e-8f);
        #pragma unroll
        for (int seg = 0; seg < 2; ++seg) {
          bf16x8 pk;
          #pragma unroll
          for (int e = 0; e < 8; ++e) {
            int kk = seg*8 + e;
            float tg = (vlen - s_gm[kk]) * s_gis[kk];
            pk[e] = (short)f2bf(__expf(-0.5f * tg * tg));
          }
          int byt = jo*256 + kh*128 + oo*32 + seg*16;
          byt ^= (jo & 7) << 4;
          *(bf16x8*)(gb + byt) = pk;
        }
      }
    }
    __syncthreads();

    // ---- T2: MFMA g = gauss @ (WgHi + WgLo) + bg ; write gout + g tile ----
    #pragma unroll 1
    for (int m = 0; m < 8; ++m) {
      floatx4 ag = {bgv, bgv, bgv, bgv};
      #pragma unroll
      for (int kr = 0; kr < 4; ++kr) {
        int row = m*16 + lo;
        int byt = (row*256 + (kr*32 + hi4*8)*2) ^ ((row & 7) << 4);
        bf16x8 a = *(const bf16x8*)(gb + byt);
        ag = __builtin_amdgcn_mfma_f32_16x16x32_bf16(a, wgf[kr*2+0], ag, 0, 0, 0);
        ag = __builtin_amdgcn_mfma_f32_16x16x32_bf16(a, wgf[kr*2+1], ag, 0, 0, 0);
      }
      int jb = jt0 + m*16 + hi4*4;
      float* gp = gout + ((size_t)bi*NN + jb)*64 + (n0 + lo);
      #pragma unroll
      for (int r = 0; r < 4; ++r) gp[r*64] = ag[r];
      #pragma unroll
      for (int r = 0; r < 4; ++r) {
        int row = m*16 + hi4*4 + r;
        int byt = (row*128 + (n0 + lo)*2) ^ ((row & 7) << 4);
        *(unsigned short*)(hb + byt) = f2bf(ag[r]);
      }
    }
    __syncthreads();

    // ---- T3a: MFMA h-pre = g @ W1 + b1 ----
    floatx4 ah[8];
    #pragma unroll 1
    for (int m = 0; m < 8; ++m) {
      floatx4 a0 = {b1v, b1v, b1v, b1v};
      #pragma unroll
      for (int kr = 0; kr < 2; ++kr) {
        int row = m*16 + lo;
        int byt = (row*128 + (kr*32 + hi4*8)*2) ^ ((row & 7) << 4);
        bf16x8 a = *(const bf16x8*)(hb + byt);
        a0 = __builtin_amdgcn_mfma_f32_16x16x32_bf16(a, w1f[kr], a0, 0, 0, 0);
      }
      ah[m] = a0;
    }
    __syncthreads();

    // ---- T3b: relu + write h over g tile ----
    #pragma unroll
    for (int m = 0; m < 8; ++m) {
      #pragma unroll
      for (int r = 0; r < 4; ++r) {
        float v = fmaxf(ah[m][r], 0.f);
        int row = m*16 + hi4*4 + r;
        int byt = (row*128 + (n0 + lo)*2) ^ ((row & 7) << 4);
        *(unsigned short*)(hb + byt) = f2bf(v);
      }
    }
    __syncthreads();

    // ---- T4: MFMA vfn = h @ W2 + b2 ; T5: qk + combine -> apre ----
    #pragma unroll 1
    for (int mm = 0; mm < 2; ++mm) {
      int m = w*2 + mm;
      floatx4 av = {b2v, b2v, b2v, b2v};
      #pragma unroll
      for (int kr = 0; kr < 2; ++kr) {
        int row = m*16 + lo;
        int byt = (row*128 + (kr*32 + hi4*8)*2) ^ ((row & 7) << 4);
        bf16x8 a = *(const bf16x8*)(hb + byt);
        av = __builtin_amdgcn_mfma_f32_16x16x32_bf16(a, w2f[kr], av, 0, 0, 0);
      }
      if (head < 12) {
        int jb = jt0 + m*16 + hi4*4;
        #pragma unroll
        for (int r = 0; r < 4; ++r) {
          int j = jb + r, jnode = b*NN + j;
          const float4* k4 = (const float4*)(act + (size_t)jnode*NCOL + 192 + head*16);
          float4 ka = k4[0], kb = k4[1], kc = k4[2], kd = k4[3];
          float qk = qv[0]*ka.x;
          qk = fmaf(qv[1], ka.y, qk);  qk = fmaf(qv[2], ka.z, qk);  qk = fmaf(qv[3], ka.w, qk);
          qk = fmaf(qv[4], kb.x, qk);  qk = fmaf(qv[5], kb.y, qk);  qk = fmaf(qv[6], kb.z, qk);
          qk = fmaf(qv[7], kb.w, qk);  qk = fmaf(qv[8], kc.x, qk);  qk = fmaf(qv[9], kc.y, qk);
          qk = fmaf(qv[10], kc.z, qk); qk = fmaf(qv[11], kc.w, qk); qk = fmaf(qv[12], kd.x, qk);
          qk = fmaf(qv[13], kd.y, qk); qk = fmaf(qv[14], kd.z, qk); qk = fmaf(qv[15], kd.w, qk);
          float d0 = trans[jnode*3]-ti0, d1 = trans[jnode*3+1]-ti1, d2 = trans[jnode*3+2]-ti2;
          float pd = 0.01f*(d0*d0 + d1*d1 + d2*d2);
          float mt = 100000.f*(mi*mask[jnode] - 1.f);
          apre[(((size_t)b*HH + head)*NN + i)*NN + j] = qk*0.125f + av[r]*0.5f + pd*hwv + mt;
        }
      }
    }
    // no barrier needed here: next T1 writes s_gauss (disjoint from s_gh reads
    // in T4); the post-T1 barrier orders s_gh reuse (all waves past T4).
  }
}

// ---------------- K3: softmax + attend ----------------
__launch_bounds__(256)
__global__ void k3_attend(const float* __restrict__ apre, const float* __restrict__ vT,
                          const float* __restrict__ vgT,
                          float* __restrict__ oout, float* __restrict__ optout)
{
  __shared__ float a4t[4][NN];     // transposed: conflict-free b32 reads
  int blk = blockIdx.x;            // B*H*(N/4)
  int ic = blk & 127; int rest = blk >> 7;
  int h = rest % HH; int b = rest / HH;
  int i0 = ic * 4;
  int t = threadIdx.x; int w = t >> 6; int l = t & 63;

  { // phase 1: wave w -> row i0+w
    int i = i0 + w;
    const float* row = apre + (((size_t)b*HH + h)*NN + i)*NN;
    float vals[8];
    float m = -1e30f;
    #pragma unroll
    for (int s8 = 0; s8 < 8; ++s8) { vals[s8] = row[l + 64*s8]; m = fmaxf(m, vals[s8]); }
    #pragma unroll
    for (int off = 1; off < 64; off <<= 1) m = fmaxf(m, __shfl_xor(m, off));
    float sum = 0.f;
    #pragma unroll
    for (int s8 = 0; s8 < 8; ++s8) { vals[s8] = __expf(vals[s8] - m); sum += vals[s8]; }
    #pragma unroll
    for (int off = 1; off < 64; off <<= 1) sum += __shfl_xor(sum, off);
    float inv = 1.f / sum;
    #pragma unroll
    for (int s8 = 0; s8 < 8; ++s8) a4t[w][l + 64*s8] = vals[s8] * inv;
  }
  __syncthreads();

  const float* vbase = vT + ((size_t)(b*HH + h)*CC)*NN;
  const float* gbase = vgT + ((size_t)(b*HH + h)*24)*NN;
  #pragma unroll 1
  for (int pass = 0; pass < 5; ++pass) {
    int c0 = w + 8*pass;
    int c1 = c0 + 4;
    const float* s0 = (c0 < 16) ? (vbase + c0*NN) : (gbase + (c0-16)*NN);
    const float* s1 = (c1 < 16) ? (vbase + c1*NN) : (gbase + (c1-16)*NN);
    float acc0[4] = {0,0,0,0}, acc1[4] = {0,0,0,0};
    #pragma unroll
    for (int s8 = 0; s8 < 8; ++s8) {
      int j = l + 64*s8;
      float a0 = a4t[0][j], a1 = a4t[1][j], a2 = a4t[2][j], a3 = a4t[3][j];
      float v0 = s0[j], v1 = s1[j];
      acc0[0] = fmaf(a0, v0, acc0[0]); acc0[1] = fmaf(a1, v0, acc0[1]);
      acc0[2] = fmaf(a2, v0, acc0[2]); acc0[3] = fmaf(a3, v0, acc0[3]);
      acc1[0] = fmaf(a0, v1, acc1[0]); acc1[1] = fmaf(a1, v1, acc1[1]);
      acc1[2] = fmaf(a2, v1, acc1[2]); acc1[3] = fmaf(a3, v1, acc1[3]);
    }
    #pragma unroll
    for (int r = 0; r < 4; ++r) {
      #pragma unroll
      for (int off = 1; off < 64; off <<= 1) {
        acc0[r] += __shfl_xor(acc0[r], off);
        acc1[r] += __shfl_xor(acc1[r], off);
      }
    }
    if (l == 0) {
      #pragma unroll
      for (int r = 0; r < 4; ++r) {
        int node = b*NN + i0 + r;
        if (c0 < 16) oout[node*192 + h*16 + c0] = acc0[r];
        else         optout[node*288 + h*24 + (c0-16)] = acc0[r];
        if (c1 < 16) oout[node*192 + h*16 + c1] = acc1[r];
        else         optout[node*288 + h*24 + (c1-16)] = acc1[r];
      }
    }
  }
}

// ---------------- K4a: build feats ----------------
__global__ void k4a_feats(const float* __restrict__ oo, const float* __restrict__ opt,
                          const float* __restrict__ rot, const float* __restrict__ trans,
                          float* __restrict__ feats)
{
  int node = blockIdx.x; int t = threadIdx.x;   // 320 threads
  float* fr = feats + node*576;
  if (t < 192) {
    fr[t] = oo[node*192 + t];
  } else if (t < 288) {
    int hp = t - 192;
    const float* R = rot + node*9;
    float tx = trans[node*3+0]*0.1f, ty = trans[node*3+1]*0.1f, tz = trans[node*3+2]*0.1f;
    const float* op = opt + (node*96 + hp)*3;
    float px = op[0]-tx, py = op[1]-ty, pz = op[2]-tz;
    float lx = R[0]*px + R[3]*py + R[6]*pz;
    float ly = R[1]*px + R[4]*py + R[7]*pz;
    float lz = R[2]*px + R[5]*py + R[8]*pz;
    float d = sqrtf(lx*lx + ly*ly + lz*lz + 1e-8f);
    fr[192+hp] = lx; fr[288+hp] = ly; fr[384+hp] = lz; fr[480+hp] = d;
  }
}

// ---------------- K4b: output projection (grid 256) ----------------
__launch_bounds__(384)
__global__ void k4b_out(const float* __restrict__ feats, const float* __restrict__ Wout,
                        const float* __restrict__ bout, float* __restrict__ sout)
{
  const int ROWS = 4;
  int row0 = blockIdx.x * ROWS;   // grid 256
  int c = threadIdx.x;            // 384
  float acc[ROWS];
  #pragma unroll
  for (int r = 0; r < ROWS; ++r) acc[r] = 0.f;
  #pragma unroll 4
  for (int f = 0; f < 576; ++f) {
    float wv = Wout[f*384 + c];
    #pragma unroll
    for (int r = 0; r < ROWS; ++r)
      acc[r] = fmaf(feats[(row0+r)*576 + f], wv, acc[r]);   // feats uniform -> scalar
  }
  float bb = bout[c];
  #pragma unroll
  for (int r = 0; r < ROWS; ++r) sout[(row0+r)*384 + c] = acc[r] + bb;
}

// ---------------- launch ----------------
extern "C" void kernel_launch(void* const* d_in, const int* in_sizes, int n_in,
                              void* d_out, int out_size, void* d_ws, size_t ws_size,
                              hipStream_t stream)
{
  const float* s     = (const float*)d_in[0];
  const float* rot   = (const float*)d_in[1];
  const float* trans = (const float*)d_in[2];
  const float* mask  = (const float*)d_in[3];
  const float* Wq    = (const float*)d_in[4];
  const float* bq    = (const float*)d_in[5];
  const float* Wkv   = (const float*)d_in[6];
  const float* bkv   = (const float*)d_in[7];
  const float* hwts  = (const float*)d_in[8];
  const float* ln_g  = (const float*)d_in[9];
  const float* ln_b  = (const float*)d_in[10];
  const float* Wpq   = (const float*)d_in[11];
  const float* bpq   = (const float*)d_in[12];
  const float* Wpv   = (const float*)d_in[13];
  const float* bpv   = (const float*)d_in[14];
  const float* Wvl   = (const float*)d_in[15];
  const float* gbm   = (const float*)d_in[16];
  const float* gbs   = (const float*)d_in[17];
  const float* Wg    = (const float*)d_in[18];
  const float* bg    = (const float*)d_in[19];
  const float* W1    = (const float*)d_in[20];
  const float* b1    = (const float*)d_in[21];
  const float* W2    = (const float*)d_in[22];
  const float* b2    = (const float*)d_in[23];
  const float* Wkvp  = (const float*)d_in[24];
  const float* bkvp  = (const float*)d_in[25];
  const float* Wout  = (const float*)d_in[26];
  const float* bout  = (const float*)d_in[27];

  float* ws = (float*)d_ws;
  float* act   = ws + 0;          // 1024*912
  float* Wbig  = ws + 933888;     // 384*912
  float* bias  = ws + 1284096;    // 912
  float* P2    = ws + 1285008;    // 912
  float* W1T   = ws + 1285920;    // 4096 (unused, layout stable)
  float* hw    = ws + 1290016;    // 16
  float* mrow  = ws + 1290032;    // 1024
  float* rstd  = ws + 1291056;    // 1024
  float* vT    = ws + 1292080;    // 196608
  float* vgT   = ws + 1488688;    // 294912
  float* apre  = ws + 1783600;    // 6291456
  float* oo    = ws + 8075056;    // 196608
  float* opt   = ws + 8271664;    // 294912
  float* feats = ws + 8566576;    // 589824
  unsigned short* wbf = (unsigned short*)(ws + 9156400);  // 21504 ushort (43KB)

  float* sout = (float*)d_out;
  float* gout = sout + BB*NN*CSZ;   // g at offset 393216

  (void)W1T;

  hipLaunchKernelGGL(k0_prep, dim3(256), dim3(256), 0, stream,
                     Wq, Wkv, Wpq, Wpv, Wkvp, bq, bkv, bpq, bpv, bkvp,
                     ln_g, ln_b, W1, hwts, Wg, W2, Wbig, bias, P2, wbf, hw);
  hipLaunchKernelGGL(k0b_stats, dim3(1024), dim3(64), 0, stream, s, mrow, rstd);
  hipLaunchKernelGGL(k1_gemm, dim3(256), dim3(256), 0, stream,
                     s, Wbig, bias, P2, mrow, rstd, act);
  hipLaunchKernelGGL(k1b_post, dim3(1920), dim3(256), 0, stream, act, rot, trans, vT, vgT);
  hipLaunchKernelGGL(k2_pair, dim3(1024), dim3(256), 0, stream,
                     act, rot, trans, mask, Wvl, gbm, gbs, wbf, bg, b1, b2, hw,
                     gout, apre);
  hipLaunchKernelGGL(k3_attend, dim3(3072), dim3(256), 0, stream, apre, vT, vgT, oo, opt);
  hipLaunchKernelGGL(k4a_feats, dim3(1024), dim3(320), 0, stream, oo, opt, rot, trans, feats);
  hipLaunchKernelGGL(k4b_out, dim3(256), dim3(384), 0, stream, feats, Wout, bout, sout);
}

// Round 9
// 453.965 us; speedup vs baseline: 1.4522x; 1.2547x over previous
//
#include <hip/hip_runtime.h>
#include <math.h>

#define BB 2
#define NN 512
#define CSZ 384
#define HH 12
#define CC 16
#define PP 8
#define PVV 8
#define KG 16
#define GG 64
#define NCOL 912
#define NODES (BB*NN)

typedef __attribute__((ext_vector_type(8))) short bf16x8;
typedef __attribute__((ext_vector_type(4))) float floatx4;

__device__ __forceinline__ unsigned short f2bf(float x) {
  unsigned u = __float_as_uint(x);
  unsigned r = (u + 0x7FFF + ((u >> 16) & 1)) >> 16;   // RNE
  return (unsigned short)r;
}

// ---------------- K0: weight prep ----------------
__global__ void k0_prep(const float* __restrict__ Wq, const float* __restrict__ Wkv,
                        const float* __restrict__ Wpq, const float* __restrict__ Wpv,
                        const float* __restrict__ Wkvp,
                        const float* __restrict__ bq, const float* __restrict__ bkv,
                        const float* __restrict__ bpq, const float* __restrict__ bpv,
                        const float* __restrict__ bkvp,
                        const float* __restrict__ ln_g, const float* __restrict__ ln_b,
                        const float* __restrict__ W1, const float* __restrict__ hwin,
                        const float* __restrict__ Wg, const float* __restrict__ W2,
                        float* __restrict__ Wbig, float* __restrict__ biasbig,
                        float* __restrict__ P2big, unsigned short* __restrict__ wbf,
                        float* __restrict__ hw)
{
  int idx = blockIdx.x*blockDim.x + threadIdx.x;
  int stride = gridDim.x*blockDim.x;
  for (int t = idx; t < CSZ*NCOL; t += stride) {
    int f = t / NCOL, c = t % NCOL;
    float w;
    if (c < 192)      w = Wq[f*192 + c];
    else if (c < 576) w = Wkv[f*384 + (c-192)];
    else if (c < 600) w = ln_g[f]*Wpq[f*24 + (c-576)];
    else if (c < 624) w = ln_g[f]*Wpv[f*24 + (c-600)];
    else              w = Wkvp[f*288 + (c-624)];
    Wbig[t] = w;
  }
  // bf16 weight pack for MFMA k2:
  // [0..8191] WgT hi [ch][pk], [8192..16383] WgT lo, [16384..20479] W1T [ho][k], [20480..21503] W2T [head][ho]
  for (int t = idx; t < 8192; t += stride) {
    int ch = t >> 7, pk = t & 127;
    float wv = Wg[pk*64 + ch];
    unsigned short h = f2bf(wv);
    float hf = __uint_as_float(((unsigned)h) << 16);
    wbf[t] = h;
    wbf[8192 + t] = f2bf(wv - hf);
  }
  for (int t = idx; t < 4096; t += stride) {
    int ho = t >> 6, k = t & 63;
    wbf[16384 + t] = f2bf(W1[k*64 + ho]);
  }
  for (int t = idx; t < 1024; t += stride) {
    int hh = t >> 6, ho = t & 63;
    wbf[20480 + t] = (hh < 12) ? f2bf(W2[ho*12 + hh]) : (unsigned short)0;
  }
  for (int c = idx; c < NCOL; c += stride) {
    float bb, p2 = 0.f;
    if (c < 192)      bb = bq[c];
    else if (c < 576) bb = bkv[c-192];
    else if (c < 624) {
      const float* W = (c < 600) ? (Wpq + (c-576)) : (Wpv + (c-600));
      float p1 = 0.f;
      for (int f = 0; f < CSZ; ++f) { p1 += ln_b[f]*W[f*24]; p2 += ln_g[f]*W[f*24]; }
      bb = ((c < 600) ? bpq[c-576] : bpv[c-600]) + p1;
    }
    else bb = bkvp[c-624];
    biasbig[c] = bb; P2big[c] = p2;
  }
  for (int h = idx; h < HH; h += stride) {
    float x = hwin[h];
    float sp = (x > 20.f) ? x : log1pf(expf(x));
    hw[h] = sp * sqrtf(1.0f/18.0f) * -0.5f;   // AFS=4, AFS*4.5=18
  }
}

// ---------------- K0b: layernorm stats ----------------
__global__ void k0b_stats(const float* __restrict__ s, float* __restrict__ mout,
                          float* __restrict__ rstdout)
{
  int node = blockIdx.x;
  int l = threadIdx.x;                 // 64 threads = 1 wave
  const float* row = s + node*CSZ;
  float sum = 0.f, sum2 = 0.f;
  for (int f = l; f < CSZ; f += 64) { float v = row[f]; sum += v; sum2 += v*v; }
  #pragma unroll
  for (int off = 1; off < 64; off <<= 1) { sum += __shfl_xor(sum, off); sum2 += __shfl_xor(sum2, off); }
  if (l == 0) {
    float m = sum / CSZ;
    float var = sum2 / CSZ - m*m;
    mout[node] = m;
    rstdout[node] = rsqrtf(var + 1e-5f);
  }
}

// ---------------- K1: fused node GEMM (grid 256) ----------------
__launch_bounds__(256)
__global__ void k1_gemm(const float* __restrict__ s, const float* __restrict__ Wbig,
                        const float* __restrict__ biasbig, const float* __restrict__ P2big,
                        const float* __restrict__ mrow, const float* __restrict__ rstd,
                        float* __restrict__ act)
{
  const int ROWS = 4;
  int row0 = blockIdx.x * ROWS;   // grid 256
  int t = threadIdx.x;            // 256
  float acc[4][ROWS];
  #pragma unroll
  for (int j = 0; j < 4; ++j)
    #pragma unroll
    for (int r = 0; r < ROWS; ++r) acc[j][r] = 0.f;

  int c3 = t + 768;
  #pragma unroll 4
  for (int f = 0; f < CSZ; ++f) {
    const float* wrow = Wbig + f*NCOL;
    float w0 = wrow[t], w1 = wrow[t+256], w2 = wrow[t+512];
    float w3 = (c3 < NCOL) ? wrow[c3] : 0.f;
    #pragma unroll
    for (int r = 0; r < ROWS; ++r) {
      float sv = s[(row0+r)*CSZ + f];     // uniform -> scalar load
      acc[0][r] = fmaf(sv, w0, acc[0][r]);
      acc[1][r] = fmaf(sv, w1, acc[1][r]);
      acc[2][r] = fmaf(sv, w2, acc[2][r]);
      acc[3][r] = fmaf(sv, w3, acc[3][r]);
    }
  }
  #pragma unroll
  for (int j = 0; j < 4; ++j) {
    int c = t + j*256;
    if (c < NCOL) {
      float bb = biasbig[c], p2v = P2big[c];
      bool lncol = (c >= 576 && c < 624);
      #pragma unroll
      for (int r = 0; r < ROWS; ++r) {
        int node = row0 + r;
        float v;
        if (lncol) { float rs = rstd[node]; v = acc[j][r]*rs + bb - mrow[node]*rs*p2v; }
        else       v = acc[j][r] + bb;
        act[node*NCOL + c] = v;
      }
    }
  }
}

// ---------------- K1b: v transpose + vg compute ----------------
__global__ void k1b_post(const float* __restrict__ act, const float* __restrict__ rot,
                         const float* __restrict__ trans,
                         float* __restrict__ vT, float* __restrict__ vgT)
{
  int idx = blockIdx.x*blockDim.x + threadIdx.x;
  const int NT1 = BB*HH*CC*NN;       // 196608
  const int NT2 = BB*HH*PVV*3*NN;    // 294912
  if (idx < NT1) {
    int n = idx & (NN-1); int rest = idx >> 9;
    int c = rest & 15; rest >>= 4;
    int h = rest % HH; int b = rest / HH;
    int node = b*NN + n;
    vT[idx] = act[node*NCOL + 192 + h*32 + 16 + c];
  } else if (idx < NT1 + NT2) {
    int j = idx - NT1;
    int n = j & (NN-1); int rest = j >> 9;
    int p3 = rest % 24; rest /= 24;
    int h = rest % HH; int b = rest / HH;
    int node = b*NN + n;
    int p = p3 / 3, x = p3 % 3;
    int hp = h*PVV + p;
    const float* kp = act + node*NCOL + 624 + hp*3;
    const float* R = rot + node*9;
    vgT[j] = R[x*3+0]*kp[0] + R[x*3+1]*kp[1] + R[x*3+2]*kp[2] + trans[node*3+x]*0.1f;
  }
}

// ---------------- K2: MFMA pair kernel (occupancy-fixed) ----------------
// grid 1024 = (b,i); 256 threads (4 waves); 4 j-tiles of 128.
// r8: worked (230us) but 1 block/CU resident (combined VGPR+AGPR > 256 ->
// 1 wave/SIMD, Occupancy 11.6%) -> all phases latency-exposed (VALU 29%,
// MFMA 3.9%). Fixes: (a) __launch_bounds__(256,2) forces 2 waves/SIMD
// (combined <=256; AGPR-parking now harmless — frags are MFMA B-operands);
// (b) drop ah[8] (32 regs) by fusing relu into T3, h written into the dead
// gauss region; (c) B-frags loaded from global wbf (L2-resident) instead of
// LDS alias-staging. Barriers: 4 per tile (T1|T2|T3|T4).
__launch_bounds__(256, 2)
__global__ void k2_pair(const float* __restrict__ act, const float* __restrict__ rot,
                        const float* __restrict__ trans, const float* __restrict__ mask,
                        const float* __restrict__ Wvl, const float* __restrict__ gm_in,
                        const float* __restrict__ gs_in,
                        const unsigned short* __restrict__ wbf,
                        const float* __restrict__ bg, const float* __restrict__ b1,
                        const float* __restrict__ b2, const float* __restrict__ hw,
                        float* __restrict__ gout, float* __restrict__ apre)
{
  __shared__ __align__(16) unsigned short s_gauss[128*128];   // 32 KB: gauss tile; h tile reuses first 16 KB
  __shared__ __align__(16) unsigned short s_g[128*64];        // 16 KB: g tile (bf16)
  __shared__ float s_qvec[24];
  __shared__ float s_q[192];
  __shared__ float s_wvl[128];
  __shared__ float s_gm[KG], s_gis[KG];
  __shared__ float s_hw[HH];

  int bi = blockIdx.x;              // b*512 + i
  int b = bi >> 9, i = bi & (NN-1);
  int t = threadIdx.x;
  int w = t >> 6, l = t & 63;
  int lo = l & 15, hi4 = l >> 4;    // C/D: col=lo, row=hi4*4+r  [m89 verified]
  const float* acti = act + (size_t)bi*NCOL;

  if (t < 24) {
    int o = t / 3, c = t % 3;
    float sum = 0.f;
    #pragma unroll
    for (int p = 0; p < PP; ++p) sum += Wvl[o*16 + 8 + p] * acti[576 + p*3 + c];
    s_qvec[t] = sum;
  } else if (t >= 32 && t < 48) {
    int k = t - 32; s_gm[k] = gm_in[k]; s_gis[k] = 1.f / gs_in[k];
  } else if (t >= 64 && t < 76) {
    s_hw[t-64] = hw[t-64];
  }
  if (t < 192) s_q[t] = acti[t];       // q rows (act cols 0..191)
  if (t < 128) s_wvl[t] = Wvl[t];

  // ---- B-frags from global wbf (VMEM, L2-resident; lane holds B[k=(l>>4)*8+e][col=l&15]) ----
  int n0 = w*16;
  bf16x8 wgf[8];   // [kr*2 + (0=hi,1=lo)]
  #pragma unroll
  for (int kr = 0; kr < 4; ++kr) {
    int el = (n0+lo)*128 + kr*32 + hi4*8;
    wgf[kr*2+0] = *(const bf16x8*)(wbf + el);
    wgf[kr*2+1] = *(const bf16x8*)(wbf + 8192 + el);
  }
  bf16x8 w1f[2], w2f[2];
  #pragma unroll
  for (int kr = 0; kr < 2; ++kr) {
    w1f[kr] = *(const bf16x8*)(wbf + 16384 + (n0+lo)*64 + kr*32 + hi4*8);
    w2f[kr] = *(const bf16x8*)(wbf + 20480 + lo*64 + kr*32 + hi4*8);
  }

  // per-lane persistent scalars
  float bgv = bg[n0 + lo];
  float b1v = b1[n0 + lo];
  int head = lo;
  float b2v = (head < 12) ? b2[head] : 0.f;
  float mi = mask[bi];
  float ti0 = trans[bi*3], ti1 = trans[bi*3+1], ti2 = trans[bi*3+2];
  float ri[9];
  #pragma unroll
  for (int q = 0; q < 9; ++q) ri[q] = rot[(size_t)bi*9 + q];
  __syncthreads();

  float hwv = s_hw[(head < 12) ? head : 0];
  float qv[16];
  {
    int hq = (head < 12) ? head : 0;
    #pragma unroll
    for (int c = 0; c < 16; ++c) qv[c] = s_q[hq*16 + c];
  }

  char* gb = (char*)s_gauss;
  char* sg = (char*)s_g;

  for (int tt = 0; tt < 4; ++tt) {
    int jt0 = tt*128;

    // ---- T1: geometry + vlen + gauss (bf16, swizzled) ----
    {
      int jo = t >> 1, kh = t & 1;          // thread -> (j-offset, k-half)
      int jnode = b*NN + jt0 + jo;
      const float* actj = act + (size_t)jnode*NCOL;
      float rj[9];
      #pragma unroll
      for (int q = 0; q < 9; ++q) rj[q] = rot[(size_t)jnode*9 + q];
      float d0 = trans[jnode*3]-ti0, d1 = trans[jnode*3+1]-ti1, d2 = trans[jnode*3+2]-ti2;
      float Rr[9];
      #pragma unroll
      for (int x = 0; x < 3; ++x)
        #pragma unroll
        for (int z = 0; z < 3; ++z)
          Rr[x*3+z] = ri[x]*rj[z] + ri[3+x]*rj[3+z] + ri[6+x]*rj[6+z];
      float tr[3];
      #pragma unroll
      for (int x = 0; x < 3; ++x) tr[x] = ri[x]*d0 + ri[3+x]*d1 + ri[6+x]*d2;
      float vpl[24];
      {
        const float4* v4 = (const float4*)(actj + 600);
        #pragma unroll
        for (int q = 0; q < 6; ++q) {
          float4 x4 = v4[q];
          vpl[q*4+0] = x4.x; vpl[q*4+1] = x4.y; vpl[q*4+2] = x4.z; vpl[q*4+3] = x4.w;
        }
      }
      #pragma unroll
      for (int p = 0; p < PP; ++p) {
        float x0 = vpl[p*3], x1 = vpl[p*3+1], x2 = vpl[p*3+2];
        float l0 = fmaf(Rr[0], x0, fmaf(Rr[1], x1, fmaf(Rr[2], x2, tr[0])));
        float l1 = fmaf(Rr[3], x0, fmaf(Rr[4], x1, fmaf(Rr[5], x2, tr[1])));
        float l2 = fmaf(Rr[6], x0, fmaf(Rr[7], x1, fmaf(Rr[8], x2, tr[2])));
        vpl[p*3] = l0; vpl[p*3+1] = l1; vpl[p*3+2] = l2;
      }
      #pragma unroll
      for (int oo = 0; oo < 4; ++oo) {
        int o = kh*4 + oo;
        float vx = vpl[o*3+0] + s_qvec[o*3+0];
        float vy = vpl[o*3+1] + s_qvec[o*3+1];
        float vz = vpl[o*3+2] + s_qvec[o*3+2];
        #pragma unroll
        for (int p = 0; p < PP; ++p) {
          float wv = s_wvl[o*16+p];
          vx = fmaf(wv, vpl[p*3+0], vx);
          vy = fmaf(wv, vpl[p*3+1], vy);
          vz = fmaf(wv, vpl[p*3+2], vz);
        }
        float vlen = sqrtf(vx*vx + vy*vy + vz*vz + 1e-8f);
        #pragma unroll
        for (int seg = 0; seg < 2; ++seg) {
          bf16x8 pk;
          #pragma unroll
          for (int e = 0; e < 8; ++e) {
            int kk = seg*8 + e;
            float tg = (vlen - s_gm[kk]) * s_gis[kk];
            pk[e] = (short)f2bf(__expf(-0.5f * tg * tg));
          }
          int byt = jo*256 + kh*128 + oo*32 + seg*16;
          byt ^= (jo & 7) << 4;
          *(bf16x8*)(gb + byt) = pk;
        }
      }
    }
    __syncthreads();

    // ---- T2: MFMA g = gauss @ (WgHi + WgLo) + bg ; write gout + g tile ----
    #pragma unroll 1
    for (int m = 0; m < 8; ++m) {
      floatx4 ag = {bgv, bgv, bgv, bgv};
      #pragma unroll
      for (int kr = 0; kr < 4; ++kr) {
        int row = m*16 + lo;
        int byt = (row*256 + (kr*32 + hi4*8)*2) ^ ((row & 7) << 4);
        bf16x8 a = *(const bf16x8*)(gb + byt);
        ag = __builtin_amdgcn_mfma_f32_16x16x32_bf16(a, wgf[kr*2+0], ag, 0, 0, 0);
        ag = __builtin_amdgcn_mfma_f32_16x16x32_bf16(a, wgf[kr*2+1], ag, 0, 0, 0);
      }
      int jb = jt0 + m*16 + hi4*4;
      float* gp = gout + ((size_t)bi*NN + jb)*64 + (n0 + lo);
      #pragma unroll
      for (int r = 0; r < 4; ++r) gp[r*64] = ag[r];
      #pragma unroll
      for (int r = 0; r < 4; ++r) {
        int row = m*16 + hi4*4 + r;
        int byt = (row*128 + (n0 + lo)*2) ^ ((row & 7) << 4);
        *(unsigned short*)(sg + byt) = f2bf(ag[r]);
      }
    }
    __syncthreads();

    // ---- T3: h = relu(g @ W1 + b1) -> gauss region (dead after T2) ----
    #pragma unroll 1
    for (int m = 0; m < 8; ++m) {
      floatx4 a0 = {b1v, b1v, b1v, b1v};
      #pragma unroll
      for (int kr = 0; kr < 2; ++kr) {
        int row = m*16 + lo;
        int byt = (row*128 + (kr*32 + hi4*8)*2) ^ ((row & 7) << 4);
        bf16x8 a = *(const bf16x8*)(sg + byt);
        a0 = __builtin_amdgcn_mfma_f32_16x16x32_bf16(a, w1f[kr], a0, 0, 0, 0);
      }
      #pragma unroll
      for (int r = 0; r < 4; ++r) {
        float v = fmaxf(a0[r], 0.f);
        int row = m*16 + hi4*4 + r;
        int byt = (row*128 + (n0 + lo)*2) ^ ((row & 7) << 4);
        *(unsigned short*)(gb + byt) = f2bf(v);
      }
    }
    __syncthreads();

    // ---- T4: MFMA vfn = h @ W2 + b2 ; T5: qk + combine -> apre ----
    #pragma unroll 1
    for (int mm = 0; mm < 2; ++mm) {
      int m = w*2 + mm;
      floatx4 av = {b2v, b2v, b2v, b2v};
      #pragma unroll
      for (int kr = 0; kr < 2; ++kr) {
        int row = m*16 + lo;
        int byt = (row*128 + (kr*32 + hi4*8)*2) ^ ((row & 7) << 4);
        bf16x8 a = *(const bf16x8*)(gb + byt);
        av = __builtin_amdgcn_mfma_f32_16x16x32_bf16(a, w2f[kr], av, 0, 0, 0);
      }
      if (head < 12) {
        int jb = jt0 + m*16 + hi4*4;
        #pragma unroll
        for (int r = 0; r < 4; ++r) {
          int j = jb + r, jnode = b*NN + j;
          const float4* k4 = (const float4*)(act + (size_t)jnode*NCOL + 192 + head*16);
          float4 ka = k4[0], kb = k4[1], kc = k4[2], kd = k4[3];
          float qk = qv[0]*ka.x;
          qk = fmaf(qv[1], ka.y, qk);  qk = fmaf(qv[2], ka.z, qk);  qk = fmaf(qv[3], ka.w, qk);
          qk = fmaf(qv[4], kb.x, qk);  qk = fmaf(qv[5], kb.y, qk);  qk = fmaf(qv[6], kb.z, qk);
          qk = fmaf(qv[7], kb.w, qk);  qk = fmaf(qv[8], kc.x, qk);  qk = fmaf(qv[9], kc.y, qk);
          qk = fmaf(qv[10], kc.z, qk); qk = fmaf(qv[11], kc.w, qk); qk = fmaf(qv[12], kd.x, qk);
          qk = fmaf(qv[13], kd.y, qk); qk = fmaf(qv[14], kd.z, qk); qk = fmaf(qv[15], kd.w, qk);
          float d0 = trans[jnode*3]-ti0, d1 = trans[jnode*3+1]-ti1, d2 = trans[jnode*3+2]-ti2;
          float pd = 0.01f*(d0*d0 + d1*d1 + d2*d2);
          float mt = 100000.f*(mi*mask[jnode] - 1.f);
          apre[(((size_t)b*HH + head)*NN + i)*NN + j] = qk*0.125f + av[r]*0.5f + pd*hwv + mt;
        }
      }
    }
    __syncthreads();   // h region (gb) must be fully read before next T1 overwrites
  }
}

// ---------------- K3: softmax + attend ----------------
__launch_bounds__(256)
__global__ void k3_attend(const float* __restrict__ apre, const float* __restrict__ vT,
                          const float* __restrict__ vgT,
                          float* __restrict__ oout, float* __restrict__ optout)
{
  __shared__ float a4t[4][NN];     // transposed: conflict-free b32 reads
  int blk = blockIdx.x;            // B*H*(N/4)
  int ic = blk & 127; int rest = blk >> 7;
  int h = rest % HH; int b = rest / HH;
  int i0 = ic * 4;
  int t = threadIdx.x; int w = t >> 6; int l = t & 63;

  { // phase 1: wave w -> row i0+w
    int i = i0 + w;
    const float* row = apre + (((size_t)b*HH + h)*NN + i)*NN;
    float vals[8];
    float m = -1e30f;
    #pragma unroll
    for (int s8 = 0; s8 < 8; ++s8) { vals[s8] = row[l + 64*s8]; m = fmaxf(m, vals[s8]); }
    #pragma unroll
    for (int off = 1; off < 64; off <<= 1) m = fmaxf(m, __shfl_xor(m, off));
    float sum = 0.f;
    #pragma unroll
    for (int s8 = 0; s8 < 8; ++s8) { vals[s8] = __expf(vals[s8] - m); sum += vals[s8]; }
    #pragma unroll
    for (int off = 1; off < 64; off <<= 1) sum += __shfl_xor(sum, off);
    float inv = 1.f / sum;
    #pragma unroll
    for (int s8 = 0; s8 < 8; ++s8) a4t[w][l + 64*s8] = vals[s8] * inv;
  }
  __syncthreads();

  const float* vbase = vT + ((size_t)(b*HH + h)*CC)*NN;
  const float* gbase = vgT + ((size_t)(b*HH + h)*24)*NN;
  #pragma unroll 1
  for (int pass = 0; pass < 5; ++pass) {
    int c0 = w + 8*pass;
    int c1 = c0 + 4;
    const float* s0 = (c0 < 16) ? (vbase + c0*NN) : (gbase + (c0-16)*NN);
    const float* s1 = (c1 < 16) ? (vbase + c1*NN) : (gbase + (c1-16)*NN);
    float acc0[4] = {0,0,0,0}, acc1[4] = {0,0,0,0};
    #pragma unroll
    for (int s8 = 0; s8 < 8; ++s8) {
      int j = l + 64*s8;
      float a0 = a4t[0][j], a1 = a4t[1][j], a2 = a4t[2][j], a3 = a4t[3][j];
      float v0 = s0[j], v1 = s1[j];
      acc0[0] = fmaf(a0, v0, acc0[0]); acc0[1] = fmaf(a1, v0, acc0[1]);
      acc0[2] = fmaf(a2, v0, acc0[2]); acc0[3] = fmaf(a3, v0, acc0[3]);
      acc1[0] = fmaf(a0, v1, acc1[0]); acc1[1] = fmaf(a1, v1, acc1[1]);
      acc1[2] = fmaf(a2, v1, acc1[2]); acc1[3] = fmaf(a3, v1, acc1[3]);
    }
    #pragma unroll
    for (int r = 0; r < 4; ++r) {
      #pragma unroll
      for (int off = 1; off < 64; off <<= 1) {
        acc0[r] += __shfl_xor(acc0[r], off);
        acc1[r] += __shfl_xor(acc1[r], off);
      }
    }
    if (l == 0) {
      #pragma unroll
      for (int r = 0; r < 4; ++r) {
        int node = b*NN + i0 + r;
        if (c0 < 16) oout[node*192 + h*16 + c0] = acc0[r];
        else         optout[node*288 + h*24 + (c0-16)] = acc0[r];
        if (c1 < 16) oout[node*192 + h*16 + c1] = acc1[r];
        else         optout[node*288 + h*24 + (c1-16)] = acc1[r];
      }
    }
  }
}

// ---------------- K4a: build feats ----------------
__global__ void k4a_feats(const float* __restrict__ oo, const float* __restrict__ opt,
                          const float* __restrict__ rot, const float* __restrict__ trans,
                          float* __restrict__ feats)
{
  int node = blockIdx.x; int t = threadIdx.x;   // 320 threads
  float* fr = feats + node*576;
  if (t < 192) {
    fr[t] = oo[node*192 + t];
  } else if (t < 288) {
    int hp = t - 192;
    const float* R = rot + node*9;
    float tx = trans[node*3+0]*0.1f, ty = trans[node*3+1]*0.1f, tz = trans[node*3+2]*0.1f;
    const float* op = opt + (node*96 + hp)*3;
    float px = op[0]-tx, py = op[1]-ty, pz = op[2]-tz;
    float lx = R[0]*px + R[3]*py + R[6]*pz;
    float ly = R[1]*px + R[4]*py + R[7]*pz;
    float lz = R[2]*px + R[5]*py + R[8]*pz;
    float d = sqrtf(lx*lx + ly*ly + lz*lz + 1e-8f);
    fr[192+hp] = lx; fr[288+hp] = ly; fr[384+hp] = lz; fr[480+hp] = d;
  }
}

// ---------------- K4b: output projection (grid 256) ----------------
__launch_bounds__(384)
__global__ void k4b_out(const float* __restrict__ feats, const float* __restrict__ Wout,
                        const float* __restrict__ bout, float* __restrict__ sout)
{
  const int ROWS = 4;
  int row0 = blockIdx.x * ROWS;   // grid 256
  int c = threadIdx.x;            // 384
  float acc[ROWS];
  #pragma unroll
  for (int r = 0; r < ROWS; ++r) acc[r] = 0.f;
  #pragma unroll 4
  for (int f = 0; f < 576; ++f) {
    float wv = Wout[f*384 + c];
    #pragma unroll
    for (int r = 0; r < ROWS; ++r)
      acc[r] = fmaf(feats[(row0+r)*576 + f], wv, acc[r]);   // feats uniform -> scalar
  }
  float bb = bout[c];
  #pragma unroll
  for (int r = 0; r < ROWS; ++r) sout[(row0+r)*384 + c] = acc[r] + bb;
}

// ---------------- launch ----------------
extern "C" void kernel_launch(void* const* d_in, const int* in_sizes, int n_in,
                              void* d_out, int out_size, void* d_ws, size_t ws_size,
                              hipStream_t stream)
{
  const float* s     = (const float*)d_in[0];
  const float* rot   = (const float*)d_in[1];
  const float* trans = (const float*)d_in[2];
  const float* mask  = (const float*)d_in[3];
  const float* Wq    = (const float*)d_in[4];
  const float* bq    = (const float*)d_in[5];
  const float* Wkv   = (const float*)d_in[6];
  const float* bkv   = (const float*)d_in[7];
  const float* hwts  = (const float*)d_in[8];
  const float* ln_g  = (const float*)d_in[9];
  const float* ln_b  = (const float*)d_in[10];
  const float* Wpq   = (const float*)d_in[11];
  const float* bpq   = (const float*)d_in[12];
  const float* Wpv   = (const float*)d_in[13];
  const float* bpv   = (const float*)d_in[14];
  const float* Wvl   = (const float*)d_in[15];
  const float* gbm   = (const float*)d_in[16];
  const float* gbs   = (const float*)d_in[17];
  const float* Wg    = (const float*)d_in[18];
  const float* bg    = (const float*)d_in[19];
  const float* W1    = (const float*)d_in[20];
  const float* b1    = (const float*)d_in[21];
  const float* W2    = (const float*)d_in[22];
  const float* b2    = (const float*)d_in[23];
  const float* Wkvp  = (const float*)d_in[24];
  const float* bkvp  = (const float*)d_in[25];
  const float* Wout  = (const float*)d_in[26];
  const float* bout  = (const float*)d_in[27];

  float* ws = (float*)d_ws;
  float* act   = ws + 0;          // 1024*912
  float* Wbig  = ws + 933888;     // 384*912
  float* bias  = ws + 1284096;    // 912
  float* P2    = ws + 1285008;    // 912
  float* W1T   = ws + 1285920;    // 4096 (unused, layout stable)
  float* hw    = ws + 1290016;    // 16
  float* mrow  = ws + 1290032;    // 1024
  float* rstd  = ws + 1291056;    // 1024
  float* vT    = ws + 1292080;    // 196608
  float* vgT   = ws + 1488688;    // 294912
  float* apre  = ws + 1783600;    // 6291456
  float* oo    = ws + 8075056;    // 196608
  float* opt   = ws + 8271664;    // 294912
  float* feats = ws + 8566576;    // 589824
  unsigned short* wbf = (unsigned short*)(ws + 9156400);  // 21504 ushort (43KB)

  float* sout = (float*)d_out;
  float* gout = sout + BB*NN*CSZ;   // g at offset 393216

  (void)W1T;

  hipLaunchKernelGGL(k0_prep, dim3(256), dim3(256), 0, stream,
                     Wq, Wkv, Wpq, Wpv, Wkvp, bq, bkv, bpq, bpv, bkvp,
                     ln_g, ln_b, W1, hwts, Wg, W2, Wbig, bias, P2, wbf, hw);
  hipLaunchKernelGGL(k0b_stats, dim3(1024), dim3(64), 0, stream, s, mrow, rstd);
  hipLaunchKernelGGL(k1_gemm, dim3(256), dim3(256), 0, stream,
                     s, Wbig, bias, P2, mrow, rstd, act);
  hipLaunchKernelGGL(k1b_post, dim3(1920), dim3(256), 0, stream, act, rot, trans, vT, vgT);
  hipLaunchKernelGGL(k2_pair, dim3(1024), dim3(256), 0, stream,
                     act, rot, trans, mask, Wvl, gbm, gbs, wbf, bg, b1, b2, hw,
                     gout, apre);
  hipLaunchKernelGGL(k3_attend, dim3(3072), dim3(256), 0, stream, apre, vT, vgT, oo, opt);
  hipLaunchKernelGGL(k4a_feats, dim3(1024), dim3(320), 0, stream, oo, opt, rot, trans, feats);
  hipLaunchKernelGGL(k4b_out, dim3(256), dim3(384), 0, stream, feats, Wout, bout, sout);
}

// Round 11
// 420.340 us; speedup vs baseline: 1.5684x; 1.0800x over previous
//
#include <hip/hip_runtime.h>
#include <math.h>

#define BB 2
#define NN 512
#define CSZ 384
#define HH 12
#define CC 16
#define PP 8
#define PVV 8
#define KG 16
#define GG 64
#define NCOL 912
#define NODES (BB*NN)

typedef __attribute__((ext_vector_type(8))) short bf16x8;
typedef __attribute__((ext_vector_type(4))) float floatx4;

__device__ __forceinline__ unsigned short f2bf(float x) {
  unsigned u = __float_as_uint(x);
  unsigned r = (u + 0x7FFF + ((u >> 16) & 1)) >> 16;   // RNE
  return (unsigned short)r;
}

// ---------------- K0: weight prep ----------------
__global__ void k0_prep(const float* __restrict__ Wq, const float* __restrict__ Wkv,
                        const float* __restrict__ Wpq, const float* __restrict__ Wpv,
                        const float* __restrict__ Wkvp,
                        const float* __restrict__ bq, const float* __restrict__ bkv,
                        const float* __restrict__ bpq, const float* __restrict__ bpv,
                        const float* __restrict__ bkvp,
                        const float* __restrict__ ln_g, const float* __restrict__ ln_b,
                        const float* __restrict__ W1, const float* __restrict__ hwin,
                        const float* __restrict__ Wg, const float* __restrict__ W2,
                        float* __restrict__ Wbig, float* __restrict__ biasbig,
                        float* __restrict__ P2big, unsigned short* __restrict__ wbf,
                        float* __restrict__ hw)
{
  int idx = blockIdx.x*blockDim.x + threadIdx.x;
  int stride = gridDim.x*blockDim.x;
  for (int t = idx; t < CSZ*NCOL; t += stride) {
    int f = t / NCOL, c = t % NCOL;
    float w;
    if (c < 192)      w = Wq[f*192 + c];
    else if (c < 576) w = Wkv[f*384 + (c-192)];
    else if (c < 600) w = ln_g[f]*Wpq[f*24 + (c-576)];
    else if (c < 624) w = ln_g[f]*Wpv[f*24 + (c-600)];
    else              w = Wkvp[f*288 + (c-624)];
    Wbig[t] = w;
  }
  // bf16 weight pack for MFMA k2:
  // [0..8191] WgT hi [ch][pk], [8192..16383] WgT lo, [16384..20479] W1T [ho][k], [20480..21503] W2T [head][ho]
  for (int t = idx; t < 8192; t += stride) {
    int ch = t >> 7, pk = t & 127;
    float wv = Wg[pk*64 + ch];
    unsigned short h = f2bf(wv);
    float hf = __uint_as_float(((unsigned)h) << 16);
    wbf[t] = h;
    wbf[8192 + t] = f2bf(wv - hf);
  }
  for (int t = idx; t < 4096; t += stride) {
    int ho = t >> 6, k = t & 63;
    wbf[16384 + t] = f2bf(W1[k*64 + ho]);
  }
  for (int t = idx; t < 1024; t += stride) {
    int hh = t >> 6, ho = t & 63;
    wbf[20480 + t] = (hh < 12) ? f2bf(W2[ho*12 + hh]) : (unsigned short)0;
  }
  // LN-bias dot products: one WAVE per column (was 48 threads x serial 384-iter
  // dependent-load loop; now 64-lane parallel reduce)
  {
    int wid = idx >> 6, lane = idx & 63;
    if (wid < 48) {
      int c = 576 + wid;
      const float* W = (c < 600) ? (Wpq + (c-576)) : (Wpv + (c-600));
      float p1 = 0.f, p2 = 0.f;
      for (int f = lane; f < CSZ; f += 64) {
        float wv = W[f*24];
        p1 = fmaf(ln_b[f], wv, p1);
        p2 = fmaf(ln_g[f], wv, p2);
      }
      #pragma unroll
      for (int off = 1; off < 64; off <<= 1) { p1 += __shfl_xor(p1, off); p2 += __shfl_xor(p2, off); }
      if (lane == 0) {
        biasbig[c] = ((c < 600) ? bpq[c-576] : bpv[c-600]) + p1;
        P2big[c] = p2;
      }
    }
  }
  for (int c = idx; c < NCOL; c += stride) {
    if (c >= 576 && c < 624) continue;   // wave path above
    float bb;
    if (c < 192)      bb = bq[c];
    else if (c < 576) bb = bkv[c-192];
    else              bb = bkvp[c-624];
    biasbig[c] = bb; P2big[c] = 0.f;
  }
  for (int h = idx; h < HH; h += stride) {
    float x = hwin[h];
    float sp = (x > 20.f) ? x : log1pf(expf(x));
    hw[h] = sp * sqrtf(1.0f/18.0f) * -0.5f;   // AFS=4, AFS*4.5=18
  }
}

// ---------------- K0b: layernorm stats ----------------
__global__ void k0b_stats(const float* __restrict__ s, float* __restrict__ mout,
                          float* __restrict__ rstdout)
{
  int node = blockIdx.x;
  int l = threadIdx.x;                 // 64 threads = 1 wave
  const float* row = s + node*CSZ;
  float sum = 0.f, sum2 = 0.f;
  for (int f = l; f < CSZ; f += 64) { float v = row[f]; sum += v; sum2 += v*v; }
  #pragma unroll
  for (int off = 1; off < 64; off <<= 1) { sum += __shfl_xor(sum, off); sum2 += __shfl_xor(sum2, off); }
  if (l == 0) {
    float m = sum / CSZ;
    float var = sum2 / CSZ - m*m;
    mout[node] = m;
    rstdout[node] = rsqrtf(var + 1e-5f);
  }
}

// ---------------- K1: fused node GEMM (grid 256) ----------------
__launch_bounds__(256)
__global__ void k1_gemm(const float* __restrict__ s, const float* __restrict__ Wbig,
                        const float* __restrict__ biasbig, const float* __restrict__ P2big,
                        const float* __restrict__ mrow, const float* __restrict__ rstd,
                        float* __restrict__ act)
{
  const int ROWS = 4;
  int row0 = blockIdx.x * ROWS;   // grid 256
  int t = threadIdx.x;            // 256
  float acc[4][ROWS];
  #pragma unroll
  for (int j = 0; j < 4; ++j)
    #pragma unroll
    for (int r = 0; r < ROWS; ++r) acc[j][r] = 0.f;

  int c3 = t + 768;
  #pragma unroll 4
  for (int f = 0; f < CSZ; ++f) {
    const float* wrow = Wbig + f*NCOL;
    float w0 = wrow[t], w1 = wrow[t+256], w2 = wrow[t+512];
    float w3 = (c3 < NCOL) ? wrow[c3] : 0.f;
    #pragma unroll
    for (int r = 0; r < ROWS; ++r) {
      float sv = s[(row0+r)*CSZ + f];     // uniform -> scalar load
      acc[0][r] = fmaf(sv, w0, acc[0][r]);
      acc[1][r] = fmaf(sv, w1, acc[1][r]);
      acc[2][r] = fmaf(sv, w2, acc[2][r]);
      acc[3][r] = fmaf(sv, w3, acc[3][r]);
    }
  }
  #pragma unroll
  for (int j = 0; j < 4; ++j) {
    int c = t + j*256;
    if (c < NCOL) {
      float bb = biasbig[c], p2v = P2big[c];
      bool lncol = (c >= 576 && c < 624);
      #pragma unroll
      for (int r = 0; r < ROWS; ++r) {
        int node = row0 + r;
        float v;
        if (lncol) { float rs = rstd[node]; v = acc[j][r]*rs + bb - mrow[node]*rs*p2v; }
        else       v = acc[j][r] + bb;
        act[node*NCOL + c] = v;
      }
    }
  }
}

// ---------------- K1b: bf16 v-panel build (for MFMA k3) ----------------
// vbf[(b*12+h)][c 0..47][j 0..511] bf16, [col][k] layout = MFMA B-operand.
// c<16: v-part of kv; 16..39: vg = R@kv_pts + ts (p3 = p*3+x); 40..47: zero pad.
__global__ void k1b_post(const float* __restrict__ act, const float* __restrict__ rot,
                         const float* __restrict__ trans,
                         unsigned short* __restrict__ vbf)
{
  int idx = blockIdx.x*blockDim.x + threadIdx.x;
  const int NT = 24*48*512;      // 589824
  if (idx >= NT) return;
  int j = idx & 511; int rest = idx >> 9;
  int c = rest % 48; int bh = rest / 48;
  int h = bh % HH, b = bh / HH;
  int node = b*NN + j;
  float v;
  if (c < 16) {
    v = act[(size_t)node*NCOL + 192 + h*32 + 16 + c];
  } else if (c < 40) {
    int p3 = c - 16;
    int p = p3 / 3, x = p3 % 3;
    int hp = h*PVV + p;
    const float* kp = act + (size_t)node*NCOL + 624 + hp*3;
    const float* R = rot + node*9;
    v = R[x*3+0]*kp[0] + R[x*3+1]*kp[1] + R[x*3+2]*kp[2] + trans[node*3+x]*0.1f;
  } else {
    v = 0.f;
  }
  vbf[idx] = f2bf(v);
}

// ---------------- K2: MFMA pair kernel ----------------
__launch_bounds__(256, 2)
__global__ void k2_pair(const float* __restrict__ act, const float* __restrict__ rot,
                        const float* __restrict__ trans, const float* __restrict__ mask,
                        const float* __restrict__ Wvl, const float* __restrict__ gm_in,
                        const float* __restrict__ gs_in,
                        const unsigned short* __restrict__ wbf,
                        const float* __restrict__ bg, const float* __restrict__ b1,
                        const float* __restrict__ b2, const float* __restrict__ hw,
                        float* __restrict__ gout, float* __restrict__ apre)
{
  __shared__ __align__(16) unsigned short s_gauss[128*128];   // 32 KB: gauss tile; h tile reuses
  __shared__ __align__(16) unsigned short s_g[128*64];        // 16 KB: g tile (bf16)
  __shared__ float s_qvec[24];
  __shared__ float s_q[192];
  __shared__ float s_wvl[128];
  __shared__ float s_gm[KG], s_gis[KG];
  __shared__ float s_hw[HH];

  int bi = blockIdx.x;              // b*512 + i
  int b = bi >> 9, i = bi & (NN-1);
  int t = threadIdx.x;
  int w = t >> 6, l = t & 63;
  int lo = l & 15, hi4 = l >> 4;    // C/D: col=lo, row=hi4*4+r  [m89 verified]
  const float* acti = act + (size_t)bi*NCOL;

  if (t < 24) {
    int o = t / 3, c = t % 3;
    float sum = 0.f;
    #pragma unroll
    for (int p = 0; p < PP; ++p) sum += Wvl[o*16 + 8 + p] * acti[576 + p*3 + c];
    s_qvec[t] = sum;
  } else if (t >= 32 && t < 48) {
    int k = t - 32; s_gm[k] = gm_in[k]; s_gis[k] = 1.f / gs_in[k];
  } else if (t >= 64 && t < 76) {
    s_hw[t-64] = hw[t-64];
  }
  if (t < 192) s_q[t] = acti[t];       // q rows (act cols 0..191)
  if (t < 128) s_wvl[t] = Wvl[t];

  // ---- B-frags from global wbf (VMEM, L2-resident) ----
  int n0 = w*16;
  bf16x8 wgf[8];   // [kr*2 + (0=hi,1=lo)]
  #pragma unroll
  for (int kr = 0; kr < 4; ++kr) {
    int el = (n0+lo)*128 + kr*32 + hi4*8;
    wgf[kr*2+0] = *(const bf16x8*)(wbf + el);
    wgf[kr*2+1] = *(const bf16x8*)(wbf + 8192 + el);
  }
  bf16x8 w1f[2], w2f[2];
  #pragma unroll
  for (int kr = 0; kr < 2; ++kr) {
    w1f[kr] = *(const bf16x8*)(wbf + 16384 + (n0+lo)*64 + kr*32 + hi4*8);
    w2f[kr] = *(const bf16x8*)(wbf + 20480 + lo*64 + kr*32 + hi4*8);
  }

  float bgv = bg[n0 + lo];
  float b1v = b1[n0 + lo];
  int head = lo;
  float b2v = (head < 12) ? b2[head] : 0.f;
  float mi = mask[bi];
  float ti0 = trans[bi*3], ti1 = trans[bi*3+1], ti2 = trans[bi*3+2];
  float ri[9];
  #pragma unroll
  for (int q = 0; q < 9; ++q) ri[q] = rot[(size_t)bi*9 + q];
  __syncthreads();

  float hwv = s_hw[(head < 12) ? head : 0];
  float qv[16];
  {
    int hq = (head < 12) ? head : 0;
    #pragma unroll
    for (int c = 0; c < 16; ++c) qv[c] = s_q[hq*16 + c];
  }

  char* gb = (char*)s_gauss;
  char* sg = (char*)s_g;

  for (int tt = 0; tt < 4; ++tt) {
    int jt0 = tt*128;

    // ---- T1: geometry + vlen + gauss (bf16, swizzled) ----
    {
      int jo = t >> 1, kh = t & 1;
      int jnode = b*NN + jt0 + jo;
      const float* actj = act + (size_t)jnode*NCOL;
      float rj[9];
      #pragma unroll
      for (int q = 0; q < 9; ++q) rj[q] = rot[(size_t)jnode*9 + q];
      float d0 = trans[jnode*3]-ti0, d1 = trans[jnode*3+1]-ti1, d2 = trans[jnode*3+2]-ti2;
      float Rr[9];
      #pragma unroll
      for (int x = 0; x < 3; ++x)
        #pragma unroll
        for (int z = 0; z < 3; ++z)
          Rr[x*3+z] = ri[x]*rj[z] + ri[3+x]*rj[3+z] + ri[6+x]*rj[6+z];
      float tr[3];
      #pragma unroll
      for (int x = 0; x < 3; ++x) tr[x] = ri[x]*d0 + ri[3+x]*d1 + ri[6+x]*d2;
      float vpl[24];
      {
        const float4* v4 = (const float4*)(actj + 600);
        #pragma unroll
        for (int q = 0; q < 6; ++q) {
          float4 x4 = v4[q];
          vpl[q*4+0] = x4.x; vpl[q*4+1] = x4.y; vpl[q*4+2] = x4.z; vpl[q*4+3] = x4.w;
        }
      }
      #pragma unroll
      for (int p = 0; p < PP; ++p) {
        float x0 = vpl[p*3], x1 = vpl[p*3+1], x2 = vpl[p*3+2];
        float l0 = fmaf(Rr[0], x0, fmaf(Rr[1], x1, fmaf(Rr[2], x2, tr[0])));
        float l1 = fmaf(Rr[3], x0, fmaf(Rr[4], x1, fmaf(Rr[5], x2, tr[1])));
        float l2 = fmaf(Rr[6], x0, fmaf(Rr[7], x1, fmaf(Rr[8], x2, tr[2])));
        vpl[p*3] = l0; vpl[p*3+1] = l1; vpl[p*3+2] = l2;
      }
      #pragma unroll
      for (int oo = 0; oo < 4; ++oo) {
        int o = kh*4 + oo;
        float vx = vpl[o*3+0] + s_qvec[o*3+0];
        float vy = vpl[o*3+1] + s_qvec[o*3+1];
        float vz = vpl[o*3+2] + s_qvec[o*3+2];
        #pragma unroll
        for (int p = 0; p < PP; ++p) {
          float wv = s_wvl[o*16+p];
          vx = fmaf(wv, vpl[p*3+0], vx);
          vy = fmaf(wv, vpl[p*3+1], vy);
          vz = fmaf(wv, vpl[p*3+2], vz);
        }
        float vlen = sqrtf(vx*vx + vy*vy + vz*vz + 1e-8f);
        #pragma unroll
        for (int seg = 0; seg < 2; ++seg) {
          bf16x8 pk;
          #pragma unroll
          for (int e = 0; e < 8; ++e) {
            int kk = seg*8 + e;
            float tg = (vlen - s_gm[kk]) * s_gis[kk];
            pk[e] = (short)f2bf(__expf(-0.5f * tg * tg));
          }
          int byt = jo*256 + kh*128 + oo*32 + seg*16;
          byt ^= (jo & 7) << 4;
          *(bf16x8*)(gb + byt) = pk;
        }
      }
    }
    __syncthreads();

    // ---- T2: MFMA g = gauss @ (WgHi + WgLo) + bg ; write gout + g tile ----
    #pragma unroll 1
    for (int m = 0; m < 8; ++m) {
      floatx4 ag = {bgv, bgv, bgv, bgv};
      #pragma unroll
      for (int kr = 0; kr < 4; ++kr) {
        int row = m*16 + lo;
        int byt = (row*256 + (kr*32 + hi4*8)*2) ^ ((row & 7) << 4);
        bf16x8 a = *(const bf16x8*)(gb + byt);
        ag = __builtin_amdgcn_mfma_f32_16x16x32_bf16(a, wgf[kr*2+0], ag, 0, 0, 0);
        ag = __builtin_amdgcn_mfma_f32_16x16x32_bf16(a, wgf[kr*2+1], ag, 0, 0, 0);
      }
      int jb = jt0 + m*16 + hi4*4;
      float* gp = gout + ((size_t)bi*NN + jb)*64 + (n0 + lo);
      #pragma unroll
      for (int r = 0; r < 4; ++r) gp[r*64] = ag[r];
      #pragma unroll
      for (int r = 0; r < 4; ++r) {
        int row = m*16 + hi4*4 + r;
        int byt = (row*128 + (n0 + lo)*2) ^ ((row & 7) << 4);
        *(unsigned short*)(sg + byt) = f2bf(ag[r]);
      }
    }
    __syncthreads();

    // ---- T3: h = relu(g @ W1 + b1) -> gauss region (dead after T2) ----
    #pragma unroll 1
    for (int m = 0; m < 8; ++m) {
      floatx4 a0 = {b1v, b1v, b1v, b1v};
      #pragma unroll
      for (int kr = 0; kr < 2; ++kr) {
        int row = m*16 + lo;
        int byt = (row*128 + (kr*32 + hi4*8)*2) ^ ((row & 7) << 4);
        bf16x8 a = *(const bf16x8*)(sg + byt);
        a0 = __builtin_amdgcn_mfma_f32_16x16x32_bf16(a, w1f[kr], a0, 0, 0, 0);
      }
      #pragma unroll
      for (int r = 0; r < 4; ++r) {
        float v = fmaxf(a0[r], 0.f);
        int row = m*16 + hi4*4 + r;
        int byt = (row*128 + (n0 + lo)*2) ^ ((row & 7) << 4);
        *(unsigned short*)(gb + byt) = f2bf(v);
      }
    }
    __syncthreads();

    // ---- T4: MFMA vfn = h @ W2 + b2 ; T5: qk + combine -> apre ----
    #pragma unroll 1
    for (int mm = 0; mm < 2; ++mm) {
      int m = w*2 + mm;
      floatx4 av = {b2v, b2v, b2v, b2v};
      #pragma unroll
      for (int kr = 0; kr < 2; ++kr) {
        int row = m*16 + lo;
        int byt = (row*128 + (kr*32 + hi4*8)*2) ^ ((row & 7) << 4);
        bf16x8 a = *(const bf16x8*)(gb + byt);
        av = __builtin_amdgcn_mfma_f32_16x16x32_bf16(a, w2f[kr], av, 0, 0, 0);
      }
      if (head < 12) {
        int jb = jt0 + m*16 + hi4*4;
        #pragma unroll
        for (int r = 0; r < 4; ++r) {
          int j = jb + r, jnode = b*NN + j;
          const float4* k4 = (const float4*)(act + (size_t)jnode*NCOL + 192 + head*16);
          float4 ka = k4[0], kb = k4[1], kc = k4[2], kd = k4[3];
          float qk = qv[0]*ka.x;
          qk = fmaf(qv[1], ka.y, qk);  qk = fmaf(qv[2], ka.z, qk);  qk = fmaf(qv[3], ka.w, qk);
          qk = fmaf(qv[4], kb.x, qk);  qk = fmaf(qv[5], kb.y, qk);  qk = fmaf(qv[6], kb.z, qk);
          qk = fmaf(qv[7], kb.w, qk);  qk = fmaf(qv[8], kc.x, qk);  qk = fmaf(qv[9], kc.y, qk);
          qk = fmaf(qv[10], kc.z, qk); qk = fmaf(qv[11], kc.w, qk); qk = fmaf(qv[12], kd.x, qk);
          qk = fmaf(qv[13], kd.y, qk); qk = fmaf(qv[14], kd.z, qk); qk = fmaf(qv[15], kd.w, qk);
          float d0 = trans[jnode*3]-ti0, d1 = trans[jnode*3+1]-ti1, d2 = trans[jnode*3+2]-ti2;
          float pd = 0.01f*(d0*d0 + d1*d1 + d2*d2);
          float mt = 100000.f*(mi*mask[jnode] - 1.f);
          apre[(((size_t)b*HH + head)*NN + i)*NN + j] = qk*0.125f + av[r]*0.5f + pd*hwv + mt;
        }
      }
    }
    __syncthreads();   // h region (gb) fully read before next T1 overwrites
  }
}

// ---------------- K3: softmax + MFMA attend ----------------
// grid 768 = 24 (b,h) x 32 i-tiles of 16 rows; 256 threads (4 waves).
// r10 BUG FIX: decomposition was blk&15/blk>>4 (bh ran 0..47, OOB apre reads
// + oout writes past buffer -> NaN). Correct: 32 itiles -> blk&31 / blk>>5.
__launch_bounds__(256)
__global__ void k3_attend(const float* __restrict__ apre, const unsigned short* __restrict__ vbf,
                          float* __restrict__ oout, float* __restrict__ optout)
{
  __shared__ __align__(16) unsigned short s_a[16*512];   // 16 KB swizzled bf16 a
  __shared__ __align__(16) float s_red[12*256];          // 12 KB partials
  int blk = blockIdx.x;            // bh*32 + itile
  int itile = blk & 31; int bh = blk >> 5;
  int h = bh % HH, b = bh / HH;
  int i0 = itile*16;
  int t = threadIdx.x; int w = t >> 6; int l = t & 63;
  int lo = l & 15, hi4 = l >> 4;

  const float* rowbase = apre + ((size_t)bh*NN + i0)*NN;

  // ---- softmax: 4 rows per wave ----
  #pragma unroll 1
  for (int rr = 0; rr < 4; ++rr) {
    int il = rr*4 + w;
    const float* row = rowbase + (size_t)il*NN;
    float vals[8];
    float m = -1e30f;
    #pragma unroll
    for (int s8 = 0; s8 < 8; ++s8) { vals[s8] = row[l + 64*s8]; m = fmaxf(m, vals[s8]); }
    #pragma unroll
    for (int off = 1; off < 64; off <<= 1) m = fmaxf(m, __shfl_xor(m, off));
    float sum = 0.f;
    #pragma unroll
    for (int s8 = 0; s8 < 8; ++s8) { vals[s8] = __expf(vals[s8] - m); sum += vals[s8]; }
    #pragma unroll
    for (int off = 1; off < 64; off <<= 1) sum += __shfl_xor(sum, off);
    float inv = 1.f / sum;
    #pragma unroll
    for (int s8 = 0; s8 < 8; ++s8) {
      int j = l + 64*s8;
      int byt = (il*1024 + j*2) ^ ((il & 7) << 4);
      *(unsigned short*)((char*)s_a + byt) = f2bf(vals[s8] * inv);
    }
  }
  __syncthreads();

  // ---- MFMA attend: wave w covers k = w*128 .. w*128+127 ----
  const unsigned short* vb = vbf + (size_t)bh*48*512;
  floatx4 acc[3];
  #pragma unroll
  for (int n = 0; n < 3; ++n) acc[n] = (floatx4){0.f, 0.f, 0.f, 0.f};
  #pragma unroll 1
  for (int ks = 0; ks < 4; ++ks) {
    int k0 = w*128 + ks*32;
    int abyte = (lo*1024 + (k0 + hi4*8)*2) ^ ((lo & 7) << 4);
    bf16x8 af = *(const bf16x8*)((char*)s_a + abyte);
    #pragma unroll
    for (int n = 0; n < 3; ++n) {
      bf16x8 bf = *(const bf16x8*)(vb + (n*16 + lo)*512 + k0 + hi4*8);
      acc[n] = __builtin_amdgcn_mfma_f32_16x16x32_bf16(af, bf, acc[n], 0, 0, 0);
    }
  }
  #pragma unroll
  for (int n = 0; n < 3; ++n)
    *(floatx4*)&s_red[((w*3 + n) << 8) + (l << 2)] = acc[n];
  __syncthreads();

  // ---- cross-wave reduce + write: wave w (<3) owns n-tile w ----
  if (w < 3) {
    floatx4 o0 = *(const floatx4*)&s_red[((0*3 + w) << 8) + (l << 2)];
    floatx4 o1 = *(const floatx4*)&s_red[((1*3 + w) << 8) + (l << 2)];
    floatx4 o2 = *(const floatx4*)&s_red[((2*3 + w) << 8) + (l << 2)];
    floatx4 o3 = *(const floatx4*)&s_red[((3*3 + w) << 8) + (l << 2)];
    int c = w*16 + lo;
    #pragma unroll
    for (int r = 0; r < 4; ++r) {
      float val = (o0[r] + o1[r]) + (o2[r] + o3[r]);
      int node = b*NN + i0 + hi4*4 + r;
      if (c < 16)      oout[node*192 + h*16 + c] = val;
      else if (c < 40) optout[node*288 + h*24 + (c-16)] = val;
    }
  }
}

// ---------------- K4a: build feats ----------------
__global__ void k4a_feats(const float* __restrict__ oo, const float* __restrict__ opt,
                          const float* __restrict__ rot, const float* __restrict__ trans,
                          float* __restrict__ feats)
{
  int node = blockIdx.x; int t = threadIdx.x;   // 320 threads
  float* fr = feats + node*576;
  if (t < 192) {
    fr[t] = oo[node*192 + t];
  } else if (t < 288) {
    int hp = t - 192;
    const float* R = rot + node*9;
    float tx = trans[node*3+0]*0.1f, ty = trans[node*3+1]*0.1f, tz = trans[node*3+2]*0.1f;
    const float* op = opt + (node*96 + hp)*3;
    float px = op[0]-tx, py = op[1]-ty, pz = op[2]-tz;
    float lx = R[0]*px + R[3]*py + R[6]*pz;
    float ly = R[1]*px + R[4]*py + R[7]*pz;
    float lz = R[2]*px + R[5]*py + R[8]*pz;
    float d = sqrtf(lx*lx + ly*ly + lz*lz + 1e-8f);
    fr[192+hp] = lx; fr[288+hp] = ly; fr[384+hp] = lz; fr[480+hp] = d;
  }
}

// ---------------- K4b: output projection (VMEM feats broadcast) ----------------
__launch_bounds__(384)
__global__ void k4b_out(const float* __restrict__ feats, const float* __restrict__ Wout,
                        const float* __restrict__ bout, float* __restrict__ sout)
{
  const int ROWS = 4;
  int row0 = blockIdx.x * ROWS;   // grid 256
  int c = threadIdx.x;            // 384
  // opaque zero -> VMEM broadcast loads (pipelined) instead of serialized s_load
  int zz; asm volatile("v_mov_b32 %0, 0" : "=v"(zz));
  const float* f0 = feats + (row0+0)*576 + zz;
  const float* f1 = feats + (row0+1)*576 + zz;
  const float* f2 = feats + (row0+2)*576 + zz;
  const float* f3 = feats + (row0+3)*576 + zz;
  float acc[ROWS];
  #pragma unroll
  for (int r = 0; r < ROWS; ++r) acc[r] = 0.f;
  #pragma unroll 4
  for (int f = 0; f < 576; ++f) {
    float wv = Wout[f*384 + c];
    acc[0] = fmaf(f0[f], wv, acc[0]);
    acc[1] = fmaf(f1[f], wv, acc[1]);
    acc[2] = fmaf(f2[f], wv, acc[2]);
    acc[3] = fmaf(f3[f], wv, acc[3]);
  }
  float bb = bout[c];
  #pragma unroll
  for (int r = 0; r < ROWS; ++r) sout[(row0+r)*384 + c] = acc[r] + bb;
}

// ---------------- launch ----------------
extern "C" void kernel_launch(void* const* d_in, const int* in_sizes, int n_in,
                              void* d_out, int out_size, void* d_ws, size_t ws_size,
                              hipStream_t stream)
{
  const float* s     = (const float*)d_in[0];
  const float* rot   = (const float*)d_in[1];
  const float* trans = (const float*)d_in[2];
  const float* mask  = (const float*)d_in[3];
  const float* Wq    = (const float*)d_in[4];
  const float* bq    = (const float*)d_in[5];
  const float* Wkv   = (const float*)d_in[6];
  const float* bkv   = (const float*)d_in[7];
  const float* hwts  = (const float*)d_in[8];
  const float* ln_g  = (const float*)d_in[9];
  const float* ln_b  = (const float*)d_in[10];
  const float* Wpq   = (const float*)d_in[11];
  const float* bpq   = (const float*)d_in[12];
  const float* Wpv   = (const float*)d_in[13];
  const float* bpv   = (const float*)d_in[14];
  const float* Wvl   = (const float*)d_in[15];
  const float* gbm   = (const float*)d_in[16];
  const float* gbs   = (const float*)d_in[17];
  const float* Wg    = (const float*)d_in[18];
  const float* bg    = (const float*)d_in[19];
  const float* W1    = (const float*)d_in[20];
  const float* b1    = (const float*)d_in[21];
  const float* W2    = (const float*)d_in[22];
  const float* b2    = (const float*)d_in[23];
  const float* Wkvp  = (const float*)d_in[24];
  const float* bkvp  = (const float*)d_in[25];
  const float* Wout  = (const float*)d_in[26];
  const float* bout  = (const float*)d_in[27];

  float* ws = (float*)d_ws;
  float* act   = ws + 0;          // 1024*912
  float* Wbig  = ws + 933888;     // 384*912
  float* bias  = ws + 1284096;    // 912
  float* P2    = ws + 1285008;    // 912
  float* hw    = ws + 1290016;    // 16
  float* mrow  = ws + 1290032;    // 1024
  float* rstd  = ws + 1291056;    // 1024
  unsigned short* vbf = (unsigned short*)(ws + 1292080);  // 589824 ushort (1.18MB)
  float* apre  = ws + 1783600;    // 6291456
  float* oo    = ws + 8075056;    // 196608
  float* opt   = ws + 8271664;    // 294912
  float* feats = ws + 8566576;    // 589824
  unsigned short* wbf = (unsigned short*)(ws + 9156400);  // 21504 ushort (43KB)

  float* sout = (float*)d_out;
  float* gout = sout + BB*NN*CSZ;   // g at offset 393216

  hipLaunchKernelGGL(k0_prep, dim3(256), dim3(256), 0, stream,
                     Wq, Wkv, Wpq, Wpv, Wkvp, bq, bkv, bpq, bpv, bkvp,
                     ln_g, ln_b, W1, hwts, Wg, W2, Wbig, bias, P2, wbf, hw);
  hipLaunchKernelGGL(k0b_stats, dim3(1024), dim3(64), 0, stream, s, mrow, rstd);
  hipLaunchKernelGGL(k1_gemm, dim3(256), dim3(256), 0, stream,
                     s, Wbig, bias, P2, mrow, rstd, act);
  hipLaunchKernelGGL(k1b_post, dim3(2304), dim3(256), 0, stream, act, rot, trans, vbf);
  hipLaunchKernelGGL(k2_pair, dim3(1024), dim3(256), 0, stream,
                     act, rot, trans, mask, Wvl, gbm, gbs, wbf, bg, b1, b2, hw,
                     gout, apre);
  hipLaunchKernelGGL(k3_attend, dim3(768), dim3(256), 0, stream, apre, vbf, oo, opt);
  hipLaunchKernelGGL(k4a_feats, dim3(1024), dim3(320), 0, stream, oo, opt, rot, trans, feats);
  hipLaunchKernelGGL(k4b_out, dim3(256), dim3(384), 0, stream, feats, Wout, bout, sout);
}